// Round 6
// baseline (243900.439 us; speedup 1.0000x reference)
//
#include <hip/hip_runtime.h>

#define TT 800
#define BB 128
#define HH 256
#define UU 64
#define AA 64
#define KK 10
#define GG 20
#define NWG 128

__device__ __forceinline__ float bf2f(unsigned short u) {
  return __uint_as_float(((unsigned int)u) << 16);
}
__device__ __forceinline__ float sigm(float x) { return 1.0f / (1.0f + __expf(-x)); }

// Read raw input element i as float, branching on sniffed dtype.
__device__ __forceinline__ float rin(const void* p, size_t i, bool f32) {
  return f32 ? ((const float*)p)[i] : bf2f(((const unsigned short*)p)[i]);
}

struct KArgs {
  const void* in[27];
  float* out;                        // fp32 output buffer (reference outputs are float32)
  float *c1, *c2, *c3, *kappa, *w;   // fp32 state
  float *h1[2], *h2[2], *h3[2];      // fp32 h double-buffers, 32768 each
  unsigned* bar;                     // [0]=count, [1]=generation
};

// Grid barrier: device-scope release/acquire atomics.
__device__ __forceinline__ void gbar(unsigned* bar) {
  __syncthreads();
  if (threadIdx.x == 0) {
    unsigned g = __hip_atomic_load(bar + 1, __ATOMIC_RELAXED, __HIP_MEMORY_SCOPE_AGENT);
    unsigned arrived =
        __hip_atomic_fetch_add(bar, 1u, __ATOMIC_ACQ_REL, __HIP_MEMORY_SCOPE_AGENT);
    if (arrived == NWG - 1u) {
      __hip_atomic_store(bar, 0u, __ATOMIC_RELAXED, __HIP_MEMORY_SCOPE_AGENT);
      __hip_atomic_store(bar + 1, g + 1u, __ATOMIC_RELEASE, __HIP_MEMORY_SCOPE_AGENT);
    } else {
      while (__hip_atomic_load(bar + 1, __ATOMIC_ACQUIRE, __HIP_MEMORY_SCOPE_AGENT) == g)
        __builtin_amdgcn_s_sleep(2);
    }
  }
  __syncthreads();
}

// Scalar LSTM gate stage: one thread per (batch, hidden unit).
// input = concat([x_t(3), w(64), hin(256 if HASH)]) @ Wih.T + rec @ Whh.T + b
template <int C, bool HASH>
__device__ void gate_scalar(const KArgs& a, bool f32, int t,
                            const void* Wih, const void* Whh, const void* bias,
                            const float* __restrict__ wv, const float* __restrict__ hin,
                            const float* __restrict__ rec,
                            float* __restrict__ cst, float* __restrict__ hout,
                            int beta, int q, int tid) {
  const int m = tid >> 2, j = tid & 3;
  const int b = beta * 64 + m;
  const int hu = q * 4 + j;
  float acc[4];
  int row[4];
#pragma unroll
  for (int g = 0; g < 4; ++g) {
    row[g] = g * HH + hu;
    acc[g] = rin(bias, row[g], f32);
  }
#pragma unroll
  for (int k = 0; k < 3; ++k) {
    float v = rin(a.in[0], ((size_t)t * BB + b) * 3 + k, f32);
#pragma unroll
    for (int g = 0; g < 4; ++g) acc[g] += v * rin(Wih, (size_t)row[g] * C + k, f32);
  }
  for (int k = 0; k < 64; ++k) {
    float v = wv[b * AA + k];
#pragma unroll
    for (int g = 0; g < 4; ++g) acc[g] += v * rin(Wih, (size_t)row[g] * C + 3 + k, f32);
  }
  if (HASH) {
    for (int k = 0; k < 256; ++k) {
      float v = hin[b * HH + k];
#pragma unroll
      for (int g = 0; g < 4; ++g) acc[g] += v * rin(Wih, (size_t)row[g] * C + 67 + k, f32);
    }
  }
  for (int k = 0; k < 256; ++k) {
    float v = rec[b * HH + k];
#pragma unroll
    for (int g = 0; g < 4; ++g) acc[g] += v * rin(Whh, (size_t)row[g] * HH + k, f32);
  }
  const int ci = b * HH + hu;
  float cn = sigm(acc[1]) * cst[ci] + sigm(acc[0]) * tanhf(acc[2]);
  cst[ci] = cn;
  hout[ci] = sigm(acc[3]) * tanhf(cn);
}

// Attention window for batch b (one WG per batch element).
__device__ void window_stage(const KArgs& a, bool f32, int b, const float* __restrict__ h1c,
                             int tid, float* misc) {
  float* shm  = misc;        // 256: h1
  float* part = misc + 256;  // 240
  float* win  = misc + 500;  // 30
  float* kap  = misc + 530;  // 10
  float* phi  = misc + 544;  // 64
  shm[tid] = h1c[b * HH + tid];
  __syncthreads();
  if (tid < 240) {
    int r = tid >> 3, pp = tid & 7;
    float s = 0.f;
#pragma unroll 8
    for (int i = 0; i < 32; ++i) s += rin(a.in[11], r * HH + pp * 32 + i, f32) * shm[pp * 32 + i];
    part[tid] = s;
  }
  __syncthreads();
  if (tid < 30) {
    float s = rin(a.in[12], tid, f32);
#pragma unroll
    for (int i = 0; i < 8; ++i) s += part[tid * 8 + i];
    win[tid] = __expf(s);
  }
  __syncthreads();
  if (tid < 10) {
    float kp = a.kappa[b * KK + tid] + 0.1f * win[20 + tid];
    a.kappa[b * KK + tid] = kp;
    kap[tid] = kp;
  }
  __syncthreads();
  if (tid < 64) {
    float u = (float)tid, s = 0.f;
#pragma unroll
    for (int r = 0; r < 10; ++r) {
      float d = kap[r] - u;
      s += win[r] * __expf(-win[10 + r] * d * d);
    }
    phi[tid] = s;
  }
  __syncthreads();
  if (tid < 64) {
    float s = 0.f;
    for (int u = 0; u < 64; ++u) s += phi[u] * rin(a.in[1], ((size_t)b * UU + u) * AA + tid, f32);
    a.w[b * AA + tid] = s;
  }
}

// Output projections for timestep tt, batch b (one WG per batch element).
__device__ void proj_stage(const KArgs& a, bool f32, int tt, const float* __restrict__ h3buf,
                           int b, int tid, float* misc) {
  float* shm  = misc;        // 256: h3
  float* part = misc + 256;  // 242
  float* zp   = misc + 500;  // 121
  shm[tid] = h3buf[b * HH + tid];
  __syncthreads();
  if (tid < 242) {
    int o = tid >> 1, hf = tid & 1;
    const void* Wt;
    const void* bt;
    int rr;
    if (o == 0) {
      Wt = a.in[13]; bt = a.in[14]; rr = 0;
    } else {
      int fam = (o - 1) / 20;
      rr = (o - 1) % 20;
      Wt = a.in[15 + fam * 2];
      bt = a.in[16 + fam * 2];
    }
    float s = hf ? 0.f : rin(bt, rr, f32);
#pragma unroll 8
    for (int i = 0; i < 128; ++i) s += rin(Wt, (size_t)rr * HH + hf * 128 + i, f32) * shm[hf * 128 + i];
    part[tid] = s;
  }
  __syncthreads();
  if (tid < 121) zp[tid] = part[tid * 2] + part[tid * 2 + 1];
  __syncthreads();
  size_t tb = (size_t)tt * BB + b;
  if (tid == 0) {
    a.out[tb] = 1.f / (1.f + __expf(zp[0]));  // sigmoid(-z)
  } else if (tid < 121) {
    int fam = (tid - 1) / 20, g = (tid - 1) % 20;
    float z = zp[tid];
    float val;
    if (fam == 0) {
      float mx = -1e30f;
      for (int jj = 0; jj < 20; ++jj) mx = fmaxf(mx, zp[1 + jj]);
      float den = 0.f;
      for (int jj = 0; jj < 20; ++jj) den += __expf(zp[1 + jj] - mx);
      val = __expf(z - mx) / den;
    } else if (fam <= 2) {
      val = z;
    } else if (fam <= 4) {
      val = __expf(z);
    } else {
      val = tanhf(z);
    }
    a.out[(size_t)102400 + (size_t)fam * 2048000 + tb * GG + g] = val;
  }
}

__global__ void __launch_bounds__(64) bar_init_kernel(unsigned* bar) {
  if (threadIdx.x < 2) bar[threadIdx.x] = 0u;
}

__global__ void __launch_bounds__(256, 1) hsm_kernel(KArgs a) {
  __shared__ float misc[768];

  const int tid = threadIdx.x;
  const int wg = blockIdx.x;
  const int beta = wg >> 6;  // batch half
  const int q = wg & 63;     // hidden quad
  unsigned* bar = a.bar;

  // ---- sniff input dtype (uniform across threads) ----
  bool isf32;
  {
    const unsigned short* w = (const unsigned short*)a.in[3];  // W1_hh
    int cnt = 0;
    for (int i = 0; i < 128; ++i) {
      float v = bf2f(w[i]);
      if (!(fabsf(v) <= 100.f)) cnt++;  // NaN-safe
    }
    isf32 = (cnt > 0);
  }

  // ---- init persistent state (ws is poisoned before every launch) ----
  {
    int g = wg * 256 + tid;  // exactly [0, 32768)
    a.c1[g] = 0.f; a.c2[g] = 0.f; a.c3[g] = 0.f;
    a.h1[0][g] = 0.f; a.h1[1][g] = 0.f;
    a.h2[0][g] = 0.f; a.h2[1][g] = 0.f;
    a.h3[0][g] = 0.f; a.h3[1][g] = 0.f;
    if (g < BB * KK) a.kappa[g] = 0.f;
    if (g < BB * AA) a.w[g] = 1.0f;  // w carry init = ones
  }
  gbar(bar);

  // prologue: LSTM1 at t=0 (rec h1=0, w=ones) -> h1[1]
  gate_scalar<67, false>(a, isf32, 0, a.in[2], a.in[3], a.in[4],
                         a.w, nullptr, a.h1[0], a.c1, a.h1[1], beta, q, tid);
  gbar(bar);

  for (int t = 0; t < TT; ++t) {
    const int p = t & 1;
    // Stage B: window(t) + projections(t-1)
    window_stage(a, isf32, wg, a.h1[1 - p], tid, misc);
    if (t > 0) proj_stage(a, isf32, t - 1, a.h3[p], wg, tid, misc);
    gbar(bar);
    // Stage C: LSTM2(t)
    gate_scalar<323, true>(a, isf32, t, a.in[5], a.in[6], a.in[7],
                           a.w, a.h1[1 - p], a.h2[p], a.c2, a.h2[1 - p], beta, q, tid);
    gbar(bar);
    // Stage D: LSTM3(t) fused with LSTM1(t+1)
    gate_scalar<323, true>(a, isf32, t, a.in[8], a.in[9], a.in[10],
                           a.w, a.h2[1 - p], a.h3[p], a.c3, a.h3[1 - p], beta, q, tid);
    if (t < TT - 1) {
      gate_scalar<67, false>(a, isf32, t + 1, a.in[2], a.in[3], a.in[4],
                             a.w, nullptr, a.h1[1 - p], a.c1, a.h1[p], beta, q, tid);
    }
    gbar(bar);
  }
  proj_stage(a, isf32, TT - 1, a.h3[0], wg, tid, misc);
}

extern "C" void kernel_launch(void* const* d_in, const int* in_sizes, int n_in,
                              void* d_out, int out_size, void* d_ws, size_t ws_size,
                              hipStream_t stream) {
  KArgs a;
  for (int i = 0; i < 27; ++i) a.in[i] = d_in[i];
  a.out = (float*)d_out;

  char* ws = (char*)d_ws;
  size_t off = 0;
  auto take = [&](size_t bytes) {
    void* p = ws + off;
    off = (off + bytes + 63) & ~(size_t)63;
    return p;
  };
  a.c1 = (float*)take(32768 * 4);
  a.c2 = (float*)take(32768 * 4);
  a.c3 = (float*)take(32768 * 4);
  a.kappa = (float*)take(1280 * 4);
  a.w = (float*)take(8192 * 4);
  a.h1[0] = (float*)take(32768 * 4);
  a.h1[1] = (float*)take(32768 * 4);
  a.h2[0] = (float*)take(32768 * 4);
  a.h2[1] = (float*)take(32768 * 4);
  a.h3[0] = (float*)take(32768 * 4);
  a.h3[1] = (float*)take(32768 * 4);
  a.bar = (unsigned*)take(2 * 4);

  bar_init_kernel<<<1, 64, 0, stream>>>(a.bar);
  hsm_kernel<<<NWG, 256, 0, stream>>>(a);
}

// Round 7
// 39764.011 us; speedup vs baseline: 6.1337x; 6.1337x over previous
//
#include <hip/hip_runtime.h>

#define TT 800
#define BB 128
#define HH 256
#define UU 64
#define AA 64
#define KK 10
#define GG 20

typedef float f32x4 __attribute__((ext_vector_type(4)));
typedef __bf16 bf16y8 __attribute__((ext_vector_type(8)));
typedef short bf16s8 __attribute__((ext_vector_type(8)));

__device__ __forceinline__ float bf2f(unsigned short u) {
  return __uint_as_float(((unsigned int)u) << 16);
}
__device__ __forceinline__ unsigned short f2bf(float f) {
  unsigned int x = __float_as_uint(f);
  x += 0x7FFFu + ((x >> 16) & 1u);
  return (unsigned short)(x >> 16);
}
__device__ __forceinline__ float sigm(float x) { return 1.0f / (1.0f + __expf(-x)); }
__device__ __forceinline__ float rin(const void* p, size_t i, bool f32) {
  return f32 ? ((const float*)p)[i] : bf2f(((const unsigned short*)p)[i]);
}
__device__ __forceinline__ bf16y8 ld8(const unsigned short* p) {
  return __builtin_bit_cast(bf16y8, *(const bf16s8*)p);
}

struct KArgs {
  const void* in[27];
  float* out;                       // fp32 outputs (reference returns float32)
  float *kappa;
  unsigned short *xh, *xl;          // x split planes, 307200 each
  unsigned short *wpl;              // w plane: hi [0,8192), lo [8192,16384)
  unsigned short *h1[2], *h2[2], *h3[2];  // hi [0,32768), lo [32768,65536)
  unsigned* bar;                    // [0..1] full-128; [16..17] grp0; [32..33] grp1
};

// release/acquire grid barrier over n arrivals (proven in r6)
__device__ __forceinline__ void gbar(unsigned* b, unsigned n) {
  __syncthreads();
  if (threadIdx.x == 0) {
    unsigned g = __hip_atomic_load(b + 1, __ATOMIC_RELAXED, __HIP_MEMORY_SCOPE_AGENT);
    unsigned arrived =
        __hip_atomic_fetch_add(b, 1u, __ATOMIC_ACQ_REL, __HIP_MEMORY_SCOPE_AGENT);
    if (arrived == n - 1u) {
      __hip_atomic_store(b, 0u, __ATOMIC_RELAXED, __HIP_MEMORY_SCOPE_AGENT);
      __hip_atomic_store(b + 1, g + 1u, __ATOMIC_RELEASE, __HIP_MEMORY_SCOPE_AGENT);
    } else {
      while (__hip_atomic_load(b + 1, __ATOMIC_ACQUIRE, __HIP_MEMORY_SCOPE_AGENT) == g)
        __builtin_amdgcn_s_sleep(2);
    }
  }
  __syncthreads();
}

// LDS B-fragment fill, hi/lo planes. Packed K: [0,3)=x, [3,8)=pad,
// [8,ihEnd)=Wih col k-5, [hhStart,hhStart+256)=Whh, rest pad.
__device__ void fillB(unsigned short* Bhi, unsigned short* Blo, const void* Wih,
                      const void* Whh, int KP, int ihCols, int ihEnd, int hhStart,
                      int q, int tid, bool f32) {
  int total = KP * 16;
  for (int idx = tid; idx < total; idx += 256) {
    int k = idx >> 4, n = idx & 15;
    int row = (n >> 2) * HH + q * 4 + (n & 3);
    float v = 0.f;
    if (k < 3) v = rin(Wih, (size_t)row * ihCols + k, f32);
    else if (k >= 8 && k < ihEnd) v = rin(Wih, (size_t)row * ihCols + (k - 5), f32);
    else if (k >= hhStart && k < hhStart + 256) v = rin(Whh, (size_t)row * HH + (k - hhStart), f32);
    unsigned short hi = f2bf(v);
    int a = ((k >> 3) * 16 + n) * 8 + (k & 7);
    Bhi[a] = hi;
    Blo[a] = f2bf(v - bf2f(hi));
  }
}

// MFMA hi/lo gate stage (datapath bit-validated vs scalar fp32, r3==r5).
// A regions: k0==0 -> x(3)+pad, [8,72) -> w, [72,328) -> r2, [328,584) -> r3.
template <int KC, bool R3>
__device__ __forceinline__ void gate_mfma(
    const unsigned short* __restrict__ xh, const unsigned short* __restrict__ xl,
    const unsigned short* __restrict__ wpl,
    const unsigned short* __restrict__ r2, const unsigned short* __restrict__ r3,
    const unsigned short* __restrict__ Bhi, const unsigned short* __restrict__ Blo,
    const float* __restrict__ bias4, float& creg, unsigned short* __restrict__ hout,
    int grp, int q, float* zls, int tid) {
  const int wave = tid >> 6, lane = tid & 63;
  const int n15 = lane & 15, quad = lane >> 4;
  const int b = grp * 64 + wave * 16 + n15;
  f32x4 acc = {0.f, 0.f, 0.f, 0.f};
#pragma unroll
  for (int kc = 0; kc < KC; ++kc) {
    const int k0 = kc * 32 + quad * 8;
    bf16y8 ah, al;
    if (kc == 0 && quad == 0) {
      bf16s8 th = {0, 0, 0, 0, 0, 0, 0, 0};
      bf16s8 tl = {0, 0, 0, 0, 0, 0, 0, 0};
      th[0] = (short)xh[b * 3 + 0]; tl[0] = (short)xl[b * 3 + 0];
      th[1] = (short)xh[b * 3 + 1]; tl[1] = (short)xl[b * 3 + 1];
      th[2] = (short)xh[b * 3 + 2]; tl[2] = (short)xl[b * 3 + 2];
      ah = __builtin_bit_cast(bf16y8, th);
      al = __builtin_bit_cast(bf16y8, tl);
    } else if (k0 < 72) {
      ah = ld8(wpl + b * 64 + (k0 - 8));
      al = ld8(wpl + 8192 + b * 64 + (k0 - 8));
    } else if (k0 < 328) {
      ah = ld8(r2 + b * 256 + (k0 - 72));
      al = ld8(r2 + 32768 + b * 256 + (k0 - 72));
    } else if (R3 && k0 < 584) {
      ah = ld8(r3 + b * 256 + (k0 - 328));
      al = ld8(r3 + 32768 + b * 256 + (k0 - 328));
    } else {
      bf16s8 t = {0, 0, 0, 0, 0, 0, 0, 0};
      ah = __builtin_bit_cast(bf16y8, t);
      al = __builtin_bit_cast(bf16y8, t);
    }
    const int boff = ((kc * 4 + quad) * 16 + n15) * 8;
    bf16y8 bh = ld8(Bhi + boff), bl = ld8(Blo + boff);
    acc = __builtin_amdgcn_mfma_f32_16x16x32_bf16(ah, bh, acc, 0, 0, 0);
    acc = __builtin_amdgcn_mfma_f32_16x16x32_bf16(ah, bl, acc, 0, 0, 0);
    acc = __builtin_amdgcn_mfma_f32_16x16x32_bf16(al, bh, acc, 0, 0, 0);
  }
  // spill D tile to wave-private LDS slice (no __syncthreads: wave-internal)
  float* zw = zls + wave * (16 * 17);
#pragma unroll
  for (int r = 0; r < 4; ++r) zw[(quad * 4 + r) * 17 + n15] = acc[r];
  const int m = lane >> 2, j = lane & 3;
  const int hu = q * 4 + j;
  const int bb = grp * 64 + wave * 16 + m;
  float zi = zw[m * 17 + (0 + j)]  + bias4[0];
  float zf = zw[m * 17 + (4 + j)]  + bias4[1];
  float zg = zw[m * 17 + (8 + j)]  + bias4[2];
  float zo = zw[m * 17 + (12 + j)] + bias4[3];
  float cn = sigm(zf) * creg + sigm(zi) * tanhf(zg);
  creg = cn;
  float hn = sigm(zo) * tanhf(cn);
  unsigned short hi = f2bf(hn);
  const int ci = bb * HH + hu;
  hout[ci] = hi;
  hout[32768 + ci] = f2bf(hn - bf2f(hi));
}

// Attention window for batch b (one WG per batch element).
template <bool F32>
__device__ void window_stage(const KArgs& a, int b, const unsigned short* __restrict__ h1c,
                             int tid, float* misc) {
  float* shm  = misc;        // 256: h1 (hi+lo reconstructed)
  float* part = misc + 256;  // 240
  float* win  = misc + 500;  // 30
  float* kap  = misc + 530;  // 10
  float* phi  = misc + 544;  // 64
  shm[tid] = bf2f(h1c[b * HH + tid]) + bf2f(h1c[32768 + b * HH + tid]);
  __syncthreads();
  if (tid < 240) {
    int r = tid >> 3, pp = tid & 7;
    float s = 0.f;
#pragma unroll 8
    for (int i = 0; i < 32; ++i) s += rin(a.in[11], r * HH + pp * 32 + i, F32) * shm[pp * 32 + i];
    part[tid] = s;
  }
  __syncthreads();
  if (tid < 30) {
    float s = rin(a.in[12], tid, F32);
#pragma unroll
    for (int i = 0; i < 8; ++i) s += part[tid * 8 + i];
    win[tid] = __expf(s);
  }
  __syncthreads();
  if (tid < 10) {
    float kp = a.kappa[b * KK + tid] + 0.1f * win[20 + tid];
    a.kappa[b * KK + tid] = kp;
    kap[tid] = kp;
  }
  __syncthreads();
  if (tid < 64) {
    float u = (float)tid, s = 0.f;
#pragma unroll
    for (int r = 0; r < 10; ++r) {
      float d = kap[r] - u;
      s += win[r] * __expf(-win[10 + r] * d * d);
    }
    phi[tid] = s;
  }
  __syncthreads();
  if (tid < 64) {
    float s = 0.f;
    for (int u = 0; u < 64; ++u) s += phi[u] * rin(a.in[1], ((size_t)b * UU + u) * AA + tid, F32);
    unsigned short hi = f2bf(s);
    a.wpl[b * AA + tid] = hi;
    a.wpl[8192 + b * AA + tid] = f2bf(s - bf2f(hi));
  }
}

// Output projections for timestep tt, batch b (one WG per batch element).
template <bool F32>
__device__ void proj_stage(const KArgs& a, int tt, const unsigned short* __restrict__ h3b,
                           int b, int tid, float* misc) {
  float* shm  = misc;        // 256: h3
  float* part = misc + 256;  // 242
  float* zp   = misc + 500;  // 121
  shm[tid] = bf2f(h3b[b * HH + tid]) + bf2f(h3b[32768 + b * HH + tid]);
  __syncthreads();
  if (tid < 242) {
    int o = tid >> 1, hf = tid & 1;
    const void* Wt;
    const void* bt;
    int rr;
    if (o == 0) {
      Wt = a.in[13]; bt = a.in[14]; rr = 0;
    } else {
      int fam = (o - 1) / 20;
      rr = (o - 1) % 20;
      Wt = a.in[15 + fam * 2];
      bt = a.in[16 + fam * 2];
    }
    float s0 = hf ? 0.f : rin(bt, rr, F32), s1 = 0.f;
    const float* hh = shm + hf * 128;
#pragma unroll 8
    for (int i = 0; i < 128; i += 2) {
      s0 += rin(Wt, (size_t)rr * HH + hf * 128 + i, F32) * hh[i];
      s1 += rin(Wt, (size_t)rr * HH + hf * 128 + i + 1, F32) * hh[i + 1];
    }
    part[tid] = s0 + s1;
  }
  __syncthreads();
  if (tid < 121) zp[tid] = part[tid * 2] + part[tid * 2 + 1];
  __syncthreads();
  size_t tb = (size_t)tt * BB + b;
  if (tid == 0) {
    a.out[tb] = 1.f / (1.f + __expf(zp[0]));  // sigmoid(-z)
  } else if (tid < 121) {
    int fam = (tid - 1) / 20, g = (tid - 1) % 20;
    float z = zp[tid];
    float val;
    if (fam == 0) {
      float mx = -1e30f;
      for (int jj = 0; jj < 20; ++jj) mx = fmaxf(mx, zp[1 + jj]);
      float den = 0.f;
      for (int jj = 0; jj < 20; ++jj) den += __expf(zp[1 + jj] - mx);
      val = __expf(z - mx) / den;
    } else if (fam <= 2) {
      val = z;
    } else if (fam <= 4) {
      val = __expf(z);
    } else {
      val = tanhf(z);
    }
    a.out[(size_t)102400 + (size_t)fam * 2048000 + tb * GG + g] = val;
  }
}

__global__ void __launch_bounds__(64) bar_init_kernel(unsigned* bar) {
  if (threadIdx.x < 48) bar[threadIdx.x] = 0u;
}

__global__ void __launch_bounds__(256, 1) hsm_kernel(KArgs a) {
  __shared__ unsigned short B1h[5632], B1l[5632];
  __shared__ unsigned short B2h[9728], B2l[9728];
  __shared__ unsigned short B3h[9728], B3l[9728];
  __shared__ float zls[4 * 16 * 17];
  __shared__ float misc[768];

  const int tid = threadIdx.x;
  const int wg = blockIdx.x;
  const int grp = wg >> 6;   // batch-half group (independent after init)
  const int q = wg & 63;     // hidden quad
  unsigned* grpbar = a.bar + 16 + grp * 16;

  // ---- dtype sniff (uniform) ----
  bool isf32;
  {
    const unsigned short* w = (const unsigned short*)a.in[3];
    int cnt = 0;
    for (int i = 0; i < 128; ++i) {
      float v = bf2f(w[i]);
      if (!(fabsf(v) <= 100.f)) cnt++;
    }
    isf32 = (cnt > 0);
  }

  // ---- init (ws poisoned before every launch) ----
  const int g0 = wg * 256 + tid, gs = 32768;
  if (isf32) {
    const float* xp = (const float*)a.in[0];
    for (int i = g0; i < 307200; i += gs) {
      float v = xp[i];
      unsigned short hi = f2bf(v);
      a.xh[i] = hi;
      a.xl[i] = f2bf(v - bf2f(hi));
    }
  } else {
    const unsigned short* xp = (const unsigned short*)a.in[0];
    for (int i = g0; i < 307200; i += gs) { a.xh[i] = xp[i]; a.xl[i] = 0; }
  }
  for (int i = g0; i < 65536; i += gs) {
    a.h1[0][i] = 0; a.h1[1][i] = 0;
    a.h2[0][i] = 0; a.h2[1][i] = 0;
    a.h3[0][i] = 0; a.h3[1][i] = 0;
  }
  if (g0 < 16384) a.wpl[g0] = (g0 < 8192) ? 0x3F80 : 0;  // w init = 1.0
  if (g0 < BB * KK) a.kappa[g0] = 0.f;

  // per-thread epilogue registers: biases + cell state
  float bs1[4], bs2[4], bs3[4];
  {
    const int hu = q * 4 + (tid & 3);
#pragma unroll
    for (int g = 0; g < 4; ++g) {
      bs1[g] = rin(a.in[4], g * HH + hu, isf32);
      bs2[g] = rin(a.in[7], g * HH + hu, isf32);
      bs3[g] = rin(a.in[10], g * HH + hu, isf32);
    }
  }
  float c1r = 0.f, c2r = 0.f, c3r = 0.f;

  fillB(B1h, B1l, a.in[2], a.in[3], 352, 67, 72, 72, q, tid, isf32);
  fillB(B2h, B2l, a.in[5], a.in[6], 608, 323, 328, 328, q, tid, isf32);
  fillB(B3h, B3l, a.in[8], a.in[9], 608, 323, 328, 328, q, tid, isf32);
  gbar(a.bar, 128);   // full barrier once: x/w/h planes visible to all

  // prologue: LSTM1(t=0): rec h1=0 (h1[0]), w=ones -> h1[1]
  gate_mfma<11, false>(a.xh, a.xl, a.wpl, a.h1[0], nullptr, B1h, B1l, bs1, c1r,
                       a.h1[1], grp, q, zls, tid);
  gbar(grpbar, 64);

  for (int t = 0; t < TT; ++t) {
    const int p = t & 1;
    const size_t xo = (size_t)t * BB * 3;
    // Stage B: window(t) + proj(t-1)
    if (isf32) {
      window_stage<true>(a, wg, a.h1[1 - p], tid, misc);
      if (t > 0) proj_stage<true>(a, t - 1, a.h3[p], wg, tid, misc);
    } else {
      window_stage<false>(a, wg, a.h1[1 - p], tid, misc);
      if (t > 0) proj_stage<false>(a, t - 1, a.h3[p], wg, tid, misc);
    }
    gbar(grpbar, 64);
    // Stage C: LSTM2(t)
    gate_mfma<19, true>(a.xh + xo, a.xl + xo, a.wpl, a.h1[1 - p], a.h2[p], B2h, B2l,
                        bs2, c2r, a.h2[1 - p], grp, q, zls, tid);
    gbar(grpbar, 64);
    // Stage D: LSTM3(t) + LSTM1(t+1)
    gate_mfma<19, true>(a.xh + xo, a.xl + xo, a.wpl, a.h2[1 - p], a.h3[p], B3h, B3l,
                        bs3, c3r, a.h3[1 - p], grp, q, zls, tid);
    if (t < TT - 1) {
      gate_mfma<11, false>(a.xh + xo + BB * 3, a.xl + xo + BB * 3, a.wpl, a.h1[1 - p],
                           nullptr, B1h, B1l, bs1, c1r, a.h1[p], grp, q, zls, tid);
    }
    gbar(grpbar, 64);
  }
  if (isf32) proj_stage<true>(a, TT - 1, a.h3[0], wg, tid, misc);
  else       proj_stage<false>(a, TT - 1, a.h3[0], wg, tid, misc);
}

extern "C" void kernel_launch(void* const* d_in, const int* in_sizes, int n_in,
                              void* d_out, int out_size, void* d_ws, size_t ws_size,
                              hipStream_t stream) {
  KArgs a;
  for (int i = 0; i < 27; ++i) a.in[i] = d_in[i];
  a.out = (float*)d_out;

  char* ws = (char*)d_ws;
  size_t off = 0;
  auto take = [&](size_t bytes) {
    void* p = ws + off;
    off = (off + bytes + 63) & ~(size_t)63;
    return p;
  };
  a.kappa = (float*)take(1280 * 4);
  a.wpl   = (unsigned short*)take(16384 * 2);
  a.h1[0] = (unsigned short*)take(65536 * 2);
  a.h1[1] = (unsigned short*)take(65536 * 2);
  a.h2[0] = (unsigned short*)take(65536 * 2);
  a.h2[1] = (unsigned short*)take(65536 * 2);
  a.h3[0] = (unsigned short*)take(65536 * 2);
  a.h3[1] = (unsigned short*)take(65536 * 2);
  a.xh    = (unsigned short*)take(307200 * 2);
  a.xl    = (unsigned short*)take(307200 * 2);
  a.bar   = (unsigned*)take(64 * 4);

  bar_init_kernel<<<1, 64, 0, stream>>>(a.bar);
  hsm_kernel<<<128, 256, 0, stream>>>(a);
}

// Round 8
// 33980.362 us; speedup vs baseline: 7.1777x; 1.1702x over previous
//
#include <hip/hip_runtime.h>

#define TT 800
#define BB 128
#define HH 256
#define UU 64
#define AA 64
#define KK 10
#define GG 20

typedef float f32x4 __attribute__((ext_vector_type(4)));
typedef __bf16 bf16y8 __attribute__((ext_vector_type(8)));
typedef short bf16s8 __attribute__((ext_vector_type(8)));

__device__ __forceinline__ float bf2f(unsigned short u) {
  return __uint_as_float(((unsigned int)u) << 16);
}
__device__ __forceinline__ unsigned short f2bf(float f) {
  unsigned int x = __float_as_uint(f);
  x += 0x7FFFu + ((x >> 16) & 1u);
  return (unsigned short)(x >> 16);
}
__device__ __forceinline__ unsigned packf(float v) {
  unsigned short hi = f2bf(v);
  unsigned short lo = f2bf(v - bf2f(hi));
  return (unsigned)hi | ((unsigned)lo << 16);
}
__device__ __forceinline__ float unpackf(unsigned u) {
  return bf2f((unsigned short)(u & 0xFFFF)) + bf2f((unsigned short)(u >> 16));
}
__device__ __forceinline__ float sigm(float x) { return 1.0f / (1.0f + __expf(-x)); }
__device__ __forceinline__ float rin(const void* p, size_t i, bool f32) {
  return f32 ? ((const float*)p)[i] : bf2f(((const unsigned short*)p)[i]);
}
__device__ __forceinline__ bf16y8 ld8(const unsigned short* p) {
  return __builtin_bit_cast(bf16y8, *(const bf16s8*)p);
}

// agent-scope relaxed atomics: plain sc1 accesses at the L3 coherence point,
// NO buffer_wbl2 / buffer_inv (those were the r7 50us/step).
__device__ __forceinline__ unsigned ald(const unsigned* p) {
  return __hip_atomic_load(p, __ATOMIC_RELAXED, __HIP_MEMORY_SCOPE_AGENT);
}
__device__ __forceinline__ void ast(unsigned* p, unsigned v) {
  __hip_atomic_store(p, v, __ATOMIC_RELAXED, __HIP_MEMORY_SCOPE_AGENT);
}

// load 8 packed elems (hi/lo planes) from an 8-aligned uint region
__device__ __forceinline__ void ld_frag(const unsigned* p, bf16y8& ah, bf16y8& al) {
  const unsigned long long* q = (const unsigned long long*)p;
  bf16s8 th, tl;
#pragma unroll
  for (int j = 0; j < 4; ++j) {
    unsigned long long u =
        __hip_atomic_load(q + j, __ATOMIC_RELAXED, __HIP_MEMORY_SCOPE_AGENT);
    unsigned a = (unsigned)u, b = (unsigned)(u >> 32);
    th[2 * j] = (short)(a & 0xFFFF);     tl[2 * j] = (short)(a >> 16);
    th[2 * j + 1] = (short)(b & 0xFFFF); tl[2 * j + 1] = (short)(b >> 16);
  }
  ah = __builtin_bit_cast(bf16y8, th);
  al = __builtin_bit_cast(bf16y8, tl);
}

struct KArgs {
  const void* in[27];
  float* out;                 // fp32 outputs
  float* kappa;               // WG-private, normal loads
  unsigned *xu;               // packed x, 307200
  unsigned *wu;               // packed w, 8192
  unsigned *h1[2], *h2[2], *h3[2];  // packed h planes, 32768 each
  unsigned* bar;              // [0]=full-grid counter; [32]=grp0; [64]=grp1
};

// fenceless counting barrier: monotone counter, caller supplies target
__device__ __forceinline__ void gbar_cnt(unsigned* slot, unsigned tgt) {
  __syncthreads();  // s_waitcnt vmcnt(0) before s_barrier drains sc1 stores to L3
  if (threadIdx.x == 0) {
    __hip_atomic_fetch_add(slot, 1u, __ATOMIC_RELAXED, __HIP_MEMORY_SCOPE_AGENT);
    while (__hip_atomic_load(slot, __ATOMIC_RELAXED, __HIP_MEMORY_SCOPE_AGENT) < tgt)
      __builtin_amdgcn_s_sleep(2);
  }
  __syncthreads();
}

// LDS B-fragment fill, hi/lo planes (unchanged from r7; read-only inputs, cached loads)
__device__ void fillB(unsigned short* Bhi, unsigned short* Blo, const void* Wih,
                      const void* Whh, int KP, int ihCols, int ihEnd, int hhStart,
                      int q, int tid, bool f32) {
  int total = KP * 16;
  for (int idx = tid; idx < total; idx += 256) {
    int k = idx >> 4, n = idx & 15;
    int row = (n >> 2) * HH + q * 4 + (n & 3);
    float v = 0.f;
    if (k < 3) v = rin(Wih, (size_t)row * ihCols + k, f32);
    else if (k >= 8 && k < ihEnd) v = rin(Wih, (size_t)row * ihCols + (k - 5), f32);
    else if (k >= hhStart && k < hhStart + 256) v = rin(Whh, (size_t)row * HH + (k - hhStart), f32);
    unsigned short hi = f2bf(v);
    int a = ((k >> 3) * 16 + n) * 8 + (k & 7);
    Bhi[a] = hi;
    Blo[a] = f2bf(v - bf2f(hi));
  }
}

// MFMA hi/lo gate stage; state planes are packed-uint sc1 (A regions as r7)
template <int KC, bool R3>
__device__ __forceinline__ void gate_mfma(
    const unsigned* __restrict__ xt, const unsigned* __restrict__ wu,
    const unsigned* __restrict__ r2, const unsigned* __restrict__ r3,
    const unsigned short* __restrict__ Bhi, const unsigned short* __restrict__ Blo,
    const float* __restrict__ bias4, float& creg, unsigned* __restrict__ hout,
    int grp, int q, float* zls, int tid) {
  const int wave = tid >> 6, lane = tid & 63;
  const int n15 = lane & 15, quad = lane >> 4;
  const int b = grp * 64 + wave * 16 + n15;
  f32x4 acc = {0.f, 0.f, 0.f, 0.f};
#pragma unroll
  for (int kc = 0; kc < KC; ++kc) {
    const int k0 = kc * 32 + quad * 8;
    bf16y8 ah, al;
    if (kc == 0 && quad == 0) {
      bf16s8 th = {0, 0, 0, 0, 0, 0, 0, 0};
      bf16s8 tl = {0, 0, 0, 0, 0, 0, 0, 0};
#pragma unroll
      for (int j = 0; j < 3; ++j) {
        unsigned u = ald(xt + b * 3 + j);
        th[j] = (short)(u & 0xFFFF);
        tl[j] = (short)(u >> 16);
      }
      ah = __builtin_bit_cast(bf16y8, th);
      al = __builtin_bit_cast(bf16y8, tl);
    } else if (k0 < 72) {
      ld_frag(wu + b * 64 + (k0 - 8), ah, al);
    } else if (k0 < 328) {
      ld_frag(r2 + b * 256 + (k0 - 72), ah, al);
    } else if (R3 && k0 < 584) {
      ld_frag(r3 + b * 256 + (k0 - 328), ah, al);
    } else {
      bf16s8 t = {0, 0, 0, 0, 0, 0, 0, 0};
      ah = __builtin_bit_cast(bf16y8, t);
      al = __builtin_bit_cast(bf16y8, t);
    }
    const int boff = ((kc * 4 + quad) * 16 + n15) * 8;
    bf16y8 bh = ld8(Bhi + boff), bl = ld8(Blo + boff);
    acc = __builtin_amdgcn_mfma_f32_16x16x32_bf16(ah, bh, acc, 0, 0, 0);
    acc = __builtin_amdgcn_mfma_f32_16x16x32_bf16(ah, bl, acc, 0, 0, 0);
    acc = __builtin_amdgcn_mfma_f32_16x16x32_bf16(al, bh, acc, 0, 0, 0);
  }
  // wave-private LDS transpose (DS ops within a wave are in-order)
  float* zw = zls + wave * (16 * 17);
#pragma unroll
  for (int r = 0; r < 4; ++r) zw[(quad * 4 + r) * 17 + n15] = acc[r];
  const int m = lane >> 2, j = lane & 3;
  const int hu = q * 4 + j;
  const int bb = grp * 64 + wave * 16 + m;
  float zi = zw[m * 17 + (0 + j)]  + bias4[0];
  float zf = zw[m * 17 + (4 + j)]  + bias4[1];
  float zg = zw[m * 17 + (8 + j)]  + bias4[2];
  float zo = zw[m * 17 + (12 + j)] + bias4[3];
  float cn = sigm(zf) * creg + sigm(zi) * tanhf(zg);
  creg = cn;
  float hn = sigm(zo) * tanhf(cn);
  ast(hout + bb * HH + hu, packf(hn));
}

// Attention window for batch b (one WG per batch element).
template <bool F32>
__device__ void window_stage(const KArgs& a, int b, const unsigned* __restrict__ h1c,
                             int tid, float* misc) {
  float* shm  = misc;        // 256
  float* part = misc + 256;  // 240
  float* win  = misc + 500;  // 30
  float* kap  = misc + 530;  // 10
  float* phi  = misc + 544;  // 64
  shm[tid] = unpackf(ald(h1c + b * HH + tid));
  __syncthreads();
  if (tid < 240) {
    int r = tid >> 3, pp = tid & 7;
    float s = 0.f;
#pragma unroll 8
    for (int i = 0; i < 32; ++i) s += rin(a.in[11], r * HH + pp * 32 + i, F32) * shm[pp * 32 + i];
    part[tid] = s;
  }
  __syncthreads();
  if (tid < 30) {
    float s = rin(a.in[12], tid, F32);
#pragma unroll
    for (int i = 0; i < 8; ++i) s += part[tid * 8 + i];
    win[tid] = __expf(s);
  }
  __syncthreads();
  if (tid < 10) {
    float kp = a.kappa[b * KK + tid] + 0.1f * win[20 + tid];
    a.kappa[b * KK + tid] = kp;
    kap[tid] = kp;
  }
  __syncthreads();
  if (tid < 64) {
    float u = (float)tid, s = 0.f;
#pragma unroll
    for (int r = 0; r < 10; ++r) {
      float d = kap[r] - u;
      s += win[r] * __expf(-win[10 + r] * d * d);
    }
    phi[tid] = s;
  }
  __syncthreads();
  if (tid < 64) {
    float s = 0.f;
    for (int u = 0; u < 64; ++u) s += phi[u] * rin(a.in[1], ((size_t)b * UU + u) * AA + tid, F32);
    ast(a.wu + b * AA + tid, packf(s));
  }
}

// Output projections for timestep tt, batch b.
template <bool F32>
__device__ void proj_stage(const KArgs& a, int tt, const unsigned* __restrict__ h3b,
                           int b, int tid, float* misc) {
  float* shm  = misc;        // 256
  float* part = misc + 256;  // 242
  float* zp   = misc + 500;  // 121
  shm[tid] = unpackf(ald(h3b + b * HH + tid));
  __syncthreads();
  if (tid < 242) {
    int o = tid >> 1, hf = tid & 1;
    const void* Wt;
    const void* bt;
    int rr;
    if (o == 0) {
      Wt = a.in[13]; bt = a.in[14]; rr = 0;
    } else {
      int fam = (o - 1) / 20;
      rr = (o - 1) % 20;
      Wt = a.in[15 + fam * 2];
      bt = a.in[16 + fam * 2];
    }
    float s0 = hf ? 0.f : rin(bt, rr, F32), s1 = 0.f;
    const float* hh = shm + hf * 128;
#pragma unroll 8
    for (int i = 0; i < 128; i += 2) {
      s0 += rin(Wt, (size_t)rr * HH + hf * 128 + i, F32) * hh[i];
      s1 += rin(Wt, (size_t)rr * HH + hf * 128 + i + 1, F32) * hh[i + 1];
    }
    part[tid] = s0 + s1;
  }
  __syncthreads();
  if (tid < 121) zp[tid] = part[tid * 2] + part[tid * 2 + 1];
  __syncthreads();
  size_t tb = (size_t)tt * BB + b;
  if (tid == 0) {
    a.out[tb] = 1.f / (1.f + __expf(zp[0]));  // sigmoid(-z)
  } else if (tid < 121) {
    int fam = (tid - 1) / 20, g = (tid - 1) % 20;
    float z = zp[tid];
    float val;
    if (fam == 0) {
      float mx = -1e30f;
      for (int jj = 0; jj < 20; ++jj) mx = fmaxf(mx, zp[1 + jj]);
      float den = 0.f;
      for (int jj = 0; jj < 20; ++jj) den += __expf(zp[1 + jj] - mx);
      val = __expf(z - mx) / den;
    } else if (fam <= 2) {
      val = z;
    } else if (fam <= 4) {
      val = __expf(z);
    } else {
      val = tanhf(z);
    }
    a.out[(size_t)102400 + (size_t)fam * 2048000 + tb * GG + g] = val;
  }
}

__global__ void __launch_bounds__(64) bar_init_kernel(unsigned* bar) {
  bar[0] = 0u; bar[32] = 0u; bar[64] = 0u;
}

__global__ void __launch_bounds__(256, 1) hsm_kernel(KArgs a) {
  __shared__ unsigned short B1h[5632], B1l[5632];
  __shared__ unsigned short B2h[9728], B2l[9728];
  __shared__ unsigned short B3h[9728], B3l[9728];
  __shared__ float zls[4 * 16 * 17];
  __shared__ float misc[768];

  const int tid = threadIdx.x;
  const int wg = blockIdx.x;
  const int grp = wg >> 6;   // batch-half group
  const int q = wg & 63;     // hidden quad
  unsigned* grpslot = a.bar + 32 + grp * 32;
  unsigned gph = 0;

  // ---- dtype sniff (uniform) ----
  bool isf32;
  {
    const unsigned short* w = (const unsigned short*)a.in[3];
    int cnt = 0;
    for (int i = 0; i < 128; ++i) {
      float v = bf2f(w[i]);
      if (!(fabsf(v) <= 100.f)) cnt++;
    }
    isf32 = (cnt > 0);
  }

  // ---- init (all cross-WG state through sc1 atomics) ----
  const int g0 = wg * 256 + tid, gs = 32768;
  if (isf32) {
    const float* xp = (const float*)a.in[0];
    for (int i = g0; i < 307200; i += gs) ast(a.xu + i, packf(xp[i]));
  } else {
    const unsigned short* xp = (const unsigned short*)a.in[0];
    for (int i = g0; i < 307200; i += gs) ast(a.xu + i, (unsigned)xp[i]);
  }
  for (int i = g0; i < 32768; i += gs) {
    ast(a.h1[0] + i, 0u); ast(a.h1[1] + i, 0u);
    ast(a.h2[0] + i, 0u); ast(a.h2[1] + i, 0u);
    ast(a.h3[0] + i, 0u); ast(a.h3[1] + i, 0u);
  }
  if (tid < 64) ast(a.wu + wg * AA + tid, 0x00003F80u);  // w init = 1.0 (hi=1.0, lo=0)
  if (tid < KK) a.kappa[wg * KK + tid] = 0.f;            // WG-private

  float bs1[4], bs2[4], bs3[4];
  {
    const int hu = q * 4 + (tid & 3);
#pragma unroll
    for (int g = 0; g < 4; ++g) {
      bs1[g] = rin(a.in[4], g * HH + hu, isf32);
      bs2[g] = rin(a.in[7], g * HH + hu, isf32);
      bs3[g] = rin(a.in[10], g * HH + hu, isf32);
    }
  }
  float c1r = 0.f, c2r = 0.f, c3r = 0.f;

  fillB(B1h, B1l, a.in[2], a.in[3], 352, 67, 72, 72, q, tid, isf32);
  fillB(B2h, B2l, a.in[5], a.in[6], 608, 323, 328, 328, q, tid, isf32);
  fillB(B3h, B3l, a.in[8], a.in[9], 608, 323, 328, 328, q, tid, isf32);
  gbar_cnt(a.bar, 128);  // full grid once: x / w / h planes at L3

  // prologue: LSTM1(t=0): rec h1[0]=0, w=ones -> h1[1]
  gate_mfma<11, false>(a.xu, a.wu, a.h1[0], nullptr, B1h, B1l, bs1, c1r,
                       a.h1[1], grp, q, zls, tid);
  ++gph; gbar_cnt(grpslot, gph * 64u);

  for (int t = 0; t < TT; ++t) {
    const int p = t & 1;
    const unsigned* xt = a.xu + (size_t)t * BB * 3;
    // Stage B: window(t) + proj(t-1)
    if (isf32) {
      window_stage<true>(a, wg, a.h1[1 - p], tid, misc);
      if (t > 0) proj_stage<true>(a, t - 1, a.h3[p], wg, tid, misc);
    } else {
      window_stage<false>(a, wg, a.h1[1 - p], tid, misc);
      if (t > 0) proj_stage<false>(a, t - 1, a.h3[p], wg, tid, misc);
    }
    ++gph; gbar_cnt(grpslot, gph * 64u);
    // Stage C: LSTM2(t)
    gate_mfma<19, true>(xt, a.wu, a.h1[1 - p], a.h2[p], B2h, B2l,
                        bs2, c2r, a.h2[1 - p], grp, q, zls, tid);
    ++gph; gbar_cnt(grpslot, gph * 64u);
    // Stage D: LSTM3(t) + LSTM1(t+1)
    gate_mfma<19, true>(xt, a.wu, a.h2[1 - p], a.h3[p], B3h, B3l,
                        bs3, c3r, a.h3[1 - p], grp, q, zls, tid);
    if (t < TT - 1) {
      gate_mfma<11, false>(xt + BB * 3, a.wu, a.h1[1 - p], nullptr,
                           B1h, B1l, bs1, c1r, a.h1[p], grp, q, zls, tid);
    }
    ++gph; gbar_cnt(grpslot, gph * 64u);
  }
  if (isf32) proj_stage<true>(a, TT - 1, a.h3[0], wg, tid, misc);
  else       proj_stage<false>(a, TT - 1, a.h3[0], wg, tid, misc);
}

extern "C" void kernel_launch(void* const* d_in, const int* in_sizes, int n_in,
                              void* d_out, int out_size, void* d_ws, size_t ws_size,
                              hipStream_t stream) {
  KArgs a;
  for (int i = 0; i < 27; ++i) a.in[i] = d_in[i];
  a.out = (float*)d_out;

  char* ws = (char*)d_ws;
  size_t off = 0;
  auto take = [&](size_t bytes) {
    void* p = ws + off;
    off = (off + bytes + 127) & ~(size_t)127;
    return p;
  };
  a.kappa = (float*)take(1280 * 4);
  a.wu    = (unsigned*)take(8192 * 4);
  a.h1[0] = (unsigned*)take(32768 * 4);
  a.h1[1] = (unsigned*)take(32768 * 4);
  a.h2[0] = (unsigned*)take(32768 * 4);
  a.h2[1] = (unsigned*)take(32768 * 4);
  a.h3[0] = (unsigned*)take(32768 * 4);
  a.h3[1] = (unsigned*)take(32768 * 4);
  a.xu    = (unsigned*)take(307200 * 4);
  a.bar   = (unsigned*)take(128 * 4);

  bar_init_kernel<<<1, 64, 0, stream>>>(a.bar);
  hsm_kernel<<<128, 256, 0, stream>>>(a);
}

// Round 9
// 31170.309 us; speedup vs baseline: 7.8248x; 1.0902x over previous
//
#include <hip/hip_runtime.h>

#define TT 800
#define BB 128
#define HH 256
#define UU 64
#define AA 64
#define KK 10
#define GG 20

typedef float f32x4 __attribute__((ext_vector_type(4)));
typedef __bf16 bf16y8 __attribute__((ext_vector_type(8)));
typedef short bf16s8 __attribute__((ext_vector_type(8)));

__device__ __forceinline__ float bf2f(unsigned short u) {
  return __uint_as_float(((unsigned int)u) << 16);
}
__device__ __forceinline__ unsigned short f2bf(float f) {
  unsigned int x = __float_as_uint(f);
  x += 0x7FFFu + ((x >> 16) & 1u);
  return (unsigned short)(x >> 16);
}
__device__ __forceinline__ unsigned packf(float v) {
  unsigned short hi = f2bf(v);
  unsigned short lo = f2bf(v - bf2f(hi));
  return (unsigned)hi | ((unsigned)lo << 16);
}
__device__ __forceinline__ float unpackf(unsigned u) {
  return bf2f((unsigned short)(u & 0xFFFF)) + bf2f((unsigned short)(u >> 16));
}
__device__ __forceinline__ float sigm(float x) { return 1.0f / (1.0f + __expf(-x)); }
__device__ __forceinline__ float rin(const void* p, size_t i, bool f32) {
  return f32 ? ((const float*)p)[i] : bf2f(((const unsigned short*)p)[i]);
}
__device__ __forceinline__ bf16y8 ld8(const unsigned short* p) {
  return __builtin_bit_cast(bf16y8, *(const bf16s8*)p);
}

// agent-scope relaxed atomics: sc1 accesses at the L3 coherence point (no wbl2/inv)
__device__ __forceinline__ unsigned ald(const unsigned* p) {
  return __hip_atomic_load(p, __ATOMIC_RELAXED, __HIP_MEMORY_SCOPE_AGENT);
}
__device__ __forceinline__ void ast(unsigned* p, unsigned v) {
  __hip_atomic_store(p, v, __ATOMIC_RELAXED, __HIP_MEMORY_SCOPE_AGENT);
}

struct KArgs {
  const void* in[27];
  float* out;
  float* kappa;               // WG-private
  unsigned *xu;               // packed x, 307200
  unsigned *wu;               // packed w, 8192
  unsigned *h1[2], *h2[2], *h3[2];  // packed h planes, 32768 each
  unsigned* bar;              // [0] full cnt; [32]/[64] grp cnts; [128+] per-WG flag lines
};

// LDS B-fragment fill, hi/lo planes (read-only inputs, cached loads)
__device__ void fillB(unsigned short* Bhi, unsigned short* Blo, const void* Wih,
                      const void* Whh, int KP, int ihCols, int ihEnd, int hhStart,
                      int q, int tid, bool f32) {
  int total = KP * 16;
  for (int idx = tid; idx < total; idx += 256) {
    int k = idx >> 4, n = idx & 15;
    int row = (n >> 2) * HH + q * 4 + (n & 3);
    float v = 0.f;
    if (k < 3) v = rin(Wih, (size_t)row * ihCols + k, f32);
    else if (k >= 8 && k < ihEnd) v = rin(Wih, (size_t)row * ihCols + (k - 5), f32);
    else if (k >= hhStart && k < hhStart + 256) v = rin(Whh, (size_t)row * HH + (k - hhStart), f32);
    unsigned short hi = f2bf(v);
    int a = ((k >> 3) * 16 + n) * 8 + (k & 7);
    Bhi[a] = hi;
    Blo[a] = f2bf(v - bf2f(hi));
  }
}

// MFMA hi/lo gate stage with depth-8 register ring prefetch of A-fragments.
// A regions: kc0/quad0 -> x(3), [8,72) -> w, [72,328) -> r2, [328,584) -> r3.
template <int KC, bool R3>
__device__ __forceinline__ void gate_mfma(
    const unsigned* __restrict__ xt, const unsigned* __restrict__ wu,
    const unsigned* __restrict__ r2, const unsigned* __restrict__ r3,
    const unsigned short* __restrict__ Bhi, const unsigned short* __restrict__ Blo,
    const float* __restrict__ bias4, float& creg, unsigned* __restrict__ hout,
    int grp, int q, float* zls, int tid) {
  const int wave = tid >> 6, lane = tid & 63;
  const int n15 = lane & 15, quad = lane >> 4;
  const int b = grp * 64 + wave * 16 + n15;

  unsigned xv0 = 0, xv1 = 0, xv2 = 0;
  if (quad == 0) {
    xv0 = ald(xt + b * 3 + 0);
    xv1 = ald(xt + b * 3 + 1);
    xv2 = ald(xt + b * 3 + 2);
  }

  constexpr int DEP = 8;
  unsigned long long buf[DEP][4];

  auto issue = [&](int kc) {
    const int k0 = kc * 32 + quad * 8;
    const unsigned* p;
    if (kc == 0 && quad == 0) p = nullptr;            // x handled via xv regs
    else if (k0 < 72) p = wu + b * 64 + (k0 - 8);
    else if (k0 < 328) p = r2 + b * 256 + (k0 - 72);
    else if (R3 && k0 < 584) p = r3 + b * 256 + (k0 - 328);
    else p = nullptr;                                  // zero pad
    unsigned long long* d = buf[kc & (DEP - 1)];
    if (p) {
      const unsigned long long* q8 = (const unsigned long long*)p;
#pragma unroll
      for (int j = 0; j < 4; ++j)
        d[j] = __hip_atomic_load(q8 + j, __ATOMIC_RELAXED, __HIP_MEMORY_SCOPE_AGENT);
    } else {
#pragma unroll
      for (int j = 0; j < 4; ++j) d[j] = 0ull;
    }
  };

#pragma unroll
  for (int kc = 0; kc < DEP && kc < KC; ++kc) issue(kc);

  f32x4 acc = {0.f, 0.f, 0.f, 0.f};
#pragma unroll
  for (int kc = 0; kc < KC; ++kc) {
    unsigned long long* s = buf[kc & (DEP - 1)];
    bf16s8 th, tl;
#pragma unroll
    for (int j = 0; j < 4; ++j) {
      unsigned lo32 = (unsigned)s[j], hi32 = (unsigned)(s[j] >> 32);
      th[2 * j] = (short)(lo32 & 0xFFFFu);     tl[2 * j] = (short)(lo32 >> 16);
      th[2 * j + 1] = (short)(hi32 & 0xFFFFu); tl[2 * j + 1] = (short)(hi32 >> 16);
    }
    if (kc == 0 && quad == 0) {
      th[0] = (short)(xv0 & 0xFFFFu); tl[0] = (short)(xv0 >> 16);
      th[1] = (short)(xv1 & 0xFFFFu); tl[1] = (short)(xv1 >> 16);
      th[2] = (short)(xv2 & 0xFFFFu); tl[2] = (short)(xv2 >> 16);
    }
    bf16y8 ah = __builtin_bit_cast(bf16y8, th);
    bf16y8 al = __builtin_bit_cast(bf16y8, tl);
    const int boff = ((kc * 4 + quad) * 16 + n15) * 8;
    bf16y8 bh = ld8(Bhi + boff), bl = ld8(Blo + boff);
    acc = __builtin_amdgcn_mfma_f32_16x16x32_bf16(ah, bh, acc, 0, 0, 0);
    acc = __builtin_amdgcn_mfma_f32_16x16x32_bf16(ah, bl, acc, 0, 0, 0);
    acc = __builtin_amdgcn_mfma_f32_16x16x32_bf16(al, bh, acc, 0, 0, 0);
    if (kc + DEP < KC) issue(kc + DEP);
  }

  // wave-private LDS transpose (wave-internal DS ordering)
  float* zw = zls + wave * (16 * 17);
#pragma unroll
  for (int r = 0; r < 4; ++r) zw[(quad * 4 + r) * 17 + n15] = acc[r];
  const int m = lane >> 2, j = lane & 3;
  const int hu = q * 4 + j;
  const int bb = grp * 64 + wave * 16 + m;
  float zi = zw[m * 17 + (0 + j)]  + bias4[0];
  float zf = zw[m * 17 + (4 + j)]  + bias4[1];
  float zg = zw[m * 17 + (8 + j)]  + bias4[2];
  float zo = zw[m * 17 + (12 + j)] + bias4[3];
  float cn = sigm(zf) * creg + sigm(zi) * tanhf(zg);
  creg = cn;
  float hn = sigm(zo) * tanhf(cn);
  ast(hout + bb * HH + hu, packf(hn));
}

// Attention window for batch b (one WG per batch element).
template <bool F32>
__device__ void window_stage(const KArgs& a, int b, const unsigned* __restrict__ h1c,
                             int tid, float* misc) {
  float* shm  = misc;        // 256
  float* part = misc + 256;  // 240
  float* win  = misc + 500;  // 30
  float* kap  = misc + 530;  // 10
  float* phi  = misc + 544;  // 64
  shm[tid] = unpackf(ald(h1c + b * HH + tid));
  __syncthreads();
  if (tid < 240) {
    int r = tid >> 3, pp = tid & 7;
    float s = 0.f;
#pragma unroll 8
    for (int i = 0; i < 32; ++i) s += rin(a.in[11], r * HH + pp * 32 + i, F32) * shm[pp * 32 + i];
    part[tid] = s;
  }
  __syncthreads();
  if (tid < 30) {
    float s = rin(a.in[12], tid, F32);
#pragma unroll
    for (int i = 0; i < 8; ++i) s += part[tid * 8 + i];
    win[tid] = __expf(s);
  }
  __syncthreads();
  if (tid < 10) {
    float kp = a.kappa[b * KK + tid] + 0.1f * win[20 + tid];
    a.kappa[b * KK + tid] = kp;
    kap[tid] = kp;
  }
  __syncthreads();
  if (tid < 64) {
    float u = (float)tid, s = 0.f;
#pragma unroll
    for (int r = 0; r < 10; ++r) {
      float d = kap[r] - u;
      s += win[r] * __expf(-win[10 + r] * d * d);
    }
    phi[tid] = s;
  }
  __syncthreads();
  if (tid < 64) {
    float s = 0.f;
    for (int u = 0; u < 64; ++u) s += phi[u] * rin(a.in[1], ((size_t)b * UU + u) * AA + tid, F32);
    ast(a.wu + b * AA + tid, packf(s));
  }
}

// Output projections for timestep tt, batch b.
template <bool F32>
__device__ void proj_stage(const KArgs& a, int tt, const unsigned* __restrict__ h3b,
                           int b, int tid, float* misc) {
  float* shm  = misc;        // 256
  float* part = misc + 256;  // 242
  float* zp   = misc + 500;  // 121
  shm[tid] = unpackf(ald(h3b + b * HH + tid));
  __syncthreads();
  if (tid < 242) {
    int o = tid >> 1, hf = tid & 1;
    const void* Wt;
    const void* bt;
    int rr;
    if (o == 0) {
      Wt = a.in[13]; bt = a.in[14]; rr = 0;
    } else {
      int fam = (o - 1) / 20;
      rr = (o - 1) % 20;
      Wt = a.in[15 + fam * 2];
      bt = a.in[16 + fam * 2];
    }
    float s0 = hf ? 0.f : rin(bt, rr, F32), s1 = 0.f;
    const float* hh = shm + hf * 128;
#pragma unroll 8
    for (int i = 0; i < 128; i += 2) {
      s0 += rin(Wt, (size_t)rr * HH + hf * 128 + i, F32) * hh[i];
      s1 += rin(Wt, (size_t)rr * HH + hf * 128 + i + 1, F32) * hh[i + 1];
    }
    part[tid] = s0 + s1;
  }
  __syncthreads();
  if (tid < 121) zp[tid] = part[tid * 2] + part[tid * 2 + 1];
  __syncthreads();
  size_t tb = (size_t)tt * BB + b;
  if (tid == 0) {
    a.out[tb] = 1.f / (1.f + __expf(zp[0]));  // sigmoid(-z)
  } else if (tid < 121) {
    int fam = (tid - 1) / 20, g = (tid - 1) % 20;
    float z = zp[tid];
    float val;
    if (fam == 0) {
      float mx = -1e30f;
      for (int jj = 0; jj < 20; ++jj) mx = fmaxf(mx, zp[1 + jj]);
      float den = 0.f;
      for (int jj = 0; jj < 20; ++jj) den += __expf(zp[1 + jj] - mx);
      val = __expf(z - mx) / den;
    } else if (fam <= 2) {
      val = z;
    } else if (fam <= 4) {
      val = __expf(z);
    } else {
      val = tanhf(z);
    }
    a.out[(size_t)102400 + (size_t)fam * 2048000 + tb * GG + g] = val;
  }
}

__global__ void __launch_bounds__(256) bar_init_kernel(unsigned* bar) {
  for (int i = threadIdx.x; i < 4224; i += 256) bar[i] = 0u;
}

__global__ void __launch_bounds__(256, 1) hsm_kernel(KArgs a) {
  __shared__ unsigned short B1h[5632], B1l[5632];
  __shared__ unsigned short B2h[9728], B2l[9728];
  __shared__ unsigned short B3h[9728], B3l[9728];
  __shared__ float zls[4 * 16 * 17];
  __shared__ float misc[768];
  __shared__ unsigned islast;

  const int tid = threadIdx.x;
  const int wg = blockIdx.x;
  const int grp = wg >> 6;   // batch-half group
  const int q = wg & 63;     // hidden quad
  unsigned* cnt_full = a.bar;
  unsigned* cnt_grp  = a.bar + 32 + grp * 32;
  unsigned* flags    = a.bar + 128;      // per-WG flag lines, 32 uints apart
  unsigned* myflag   = flags + wg * 32;

  // broadcast barrier: one fetch_add per WG; last arriver (known from return
  // value, no polling) broadcasts phase to per-WG private flag lines.
  auto barrier = [&](unsigned* cnt, unsigned target, unsigned fv, int nfl, int flbase) {
    __syncthreads();   // drains this WG's sc1 stores (vmcnt(0) before s_barrier)
    if (tid == 0) {
      unsigned old = __hip_atomic_fetch_add(cnt, 1u, __ATOMIC_RELAXED,
                                            __HIP_MEMORY_SCOPE_AGENT);
      islast = (old == target - 1u) ? 1u : 0u;
    }
    __syncthreads();
    if (islast) {
      if (tid < nfl) ast(flags + (flbase + tid) * 32, fv);
    } else if (tid == 0) {
      while (ald(myflag) < fv) __builtin_amdgcn_s_sleep(2);
    }
    __syncthreads();
  };

  // ---- dtype sniff (uniform) ----
  bool isf32;
  {
    const unsigned short* w = (const unsigned short*)a.in[3];
    int cnt = 0;
    for (int i = 0; i < 128; ++i) {
      float v = bf2f(w[i]);
      if (!(fabsf(v) <= 100.f)) cnt++;
    }
    isf32 = (cnt > 0);
  }

  // ---- init (all cross-WG state through sc1 atomics) ----
  const int g0 = wg * 256 + tid, gs = 32768;
  if (isf32) {
    const float* xp = (const float*)a.in[0];
    for (int i = g0; i < 307200; i += gs) ast(a.xu + i, packf(xp[i]));
  } else {
    const unsigned short* xp = (const unsigned short*)a.in[0];
    for (int i = g0; i < 307200; i += gs) ast(a.xu + i, (unsigned)xp[i]);
  }
  for (int i = g0; i < 32768; i += gs) {
    ast(a.h1[0] + i, 0u); ast(a.h1[1] + i, 0u);
    ast(a.h2[0] + i, 0u); ast(a.h2[1] + i, 0u);
    ast(a.h3[0] + i, 0u); ast(a.h3[1] + i, 0u);
  }
  if (tid < 64) ast(a.wu + wg * AA + tid, 0x00003F80u);  // w init = 1.0
  if (tid < KK) a.kappa[wg * KK + tid] = 0.f;

  float bs1[4], bs2[4], bs3[4];
  {
    const int hu = q * 4 + (tid & 3);
#pragma unroll
    for (int g = 0; g < 4; ++g) {
      bs1[g] = rin(a.in[4], g * HH + hu, isf32);
      bs2[g] = rin(a.in[7], g * HH + hu, isf32);
      bs3[g] = rin(a.in[10], g * HH + hu, isf32);
    }
  }
  float c1r = 0.f, c2r = 0.f, c3r = 0.f;

  fillB(B1h, B1l, a.in[2], a.in[3], 352, 67, 72, 72, q, tid, isf32);
  fillB(B2h, B2l, a.in[5], a.in[6], 608, 323, 328, 328, q, tid, isf32);
  fillB(B3h, B3l, a.in[8], a.in[9], 608, 323, 328, 328, q, tid, isf32);
  barrier(cnt_full, 128, 1, 128, 0);     // full grid once

  unsigned ph = 0;  // group-barrier phase; flag value = ph+1 (init wrote 1)

  // prologue: LSTM1(t=0): rec h1[0]=0, w=ones -> h1[1]
  gate_mfma<11, false>(a.xu, a.wu, a.h1[0], nullptr, B1h, B1l, bs1, c1r,
                       a.h1[1], grp, q, zls, tid);
  ++ph; barrier(cnt_grp, ph * 64u, ph + 1u, 64, grp * 64);

  for (int t = 0; t < TT; ++t) {
    const int p = t & 1;
    const unsigned* xt = a.xu + (size_t)t * BB * 3;
    // Stage B: window(t) + proj(t-1)
    if (isf32) {
      window_stage<true>(a, wg, a.h1[1 - p], tid, misc);
      if (t > 0) proj_stage<true>(a, t - 1, a.h3[p], wg, tid, misc);
    } else {
      window_stage<false>(a, wg, a.h1[1 - p], tid, misc);
      if (t > 0) proj_stage<false>(a, t - 1, a.h3[p], wg, tid, misc);
    }
    ++ph; barrier(cnt_grp, ph * 64u, ph + 1u, 64, grp * 64);
    // Stage C: LSTM2(t)
    gate_mfma<19, true>(xt, a.wu, a.h1[1 - p], a.h2[p], B2h, B2l,
                        bs2, c2r, a.h2[1 - p], grp, q, zls, tid);
    ++ph; barrier(cnt_grp, ph * 64u, ph + 1u, 64, grp * 64);
    // Stage D: LSTM3(t) + LSTM1(t+1)
    gate_mfma<19, true>(xt, a.wu, a.h2[1 - p], a.h3[p], B3h, B3l,
                        bs3, c3r, a.h3[1 - p], grp, q, zls, tid);
    if (t < TT - 1) {
      gate_mfma<11, false>(xt + BB * 3, a.wu, a.h1[1 - p], nullptr,
                           B1h, B1l, bs1, c1r, a.h1[p], grp, q, zls, tid);
    }
    ++ph; barrier(cnt_grp, ph * 64u, ph + 1u, 64, grp * 64);
  }
  if (isf32) proj_stage<true>(a, TT - 1, a.h3[0], wg, tid, misc);
  else       proj_stage<false>(a, TT - 1, a.h3[0], wg, tid, misc);
}

extern "C" void kernel_launch(void* const* d_in, const int* in_sizes, int n_in,
                              void* d_out, int out_size, void* d_ws, size_t ws_size,
                              hipStream_t stream) {
  KArgs a;
  for (int i = 0; i < 27; ++i) a.in[i] = d_in[i];
  a.out = (float*)d_out;

  char* ws = (char*)d_ws;
  size_t off = 0;
  auto take = [&](size_t bytes) {
    void* p = ws + off;
    off = (off + bytes + 127) & ~(size_t)127;
    return p;
  };
  a.kappa = (float*)take(1280 * 4);
  a.wu    = (unsigned*)take(8192 * 4);
  a.h1[0] = (unsigned*)take(32768 * 4);
  a.h1[1] = (unsigned*)take(32768 * 4);
  a.h2[0] = (unsigned*)take(32768 * 4);
  a.h2[1] = (unsigned*)take(32768 * 4);
  a.h3[0] = (unsigned*)take(32768 * 4);
  a.h3[1] = (unsigned*)take(32768 * 4);
  a.xu    = (unsigned*)take(307200 * 4);
  a.bar   = (unsigned*)take(4224 * 4);

  bar_init_kernel<<<1, 256, 0, stream>>>(a.bar);
  hsm_kernel<<<128, 256, 0, stream>>>(a);
}

// Round 10
// 20049.719 us; speedup vs baseline: 12.1648x; 1.5547x over previous
//
#include <hip/hip_runtime.h>

#define TT 800
#define BB 128
#define HH 256
#define UU 64
#define AA 64
#define KK 10
#define GG 20
#define NWG 256
#define GB 32          // batches per group
#define NGRP 4

typedef float f32x4 __attribute__((ext_vector_type(4)));
typedef __bf16 bf16y8 __attribute__((ext_vector_type(8)));
typedef short bf16s8 __attribute__((ext_vector_type(8)));

__device__ __forceinline__ float bf2f(unsigned short u) {
  return __uint_as_float(((unsigned int)u) << 16);
}
__device__ __forceinline__ unsigned short f2bf(float f) {
  unsigned int x = __float_as_uint(f);
  x += 0x7FFFu + ((x >> 16) & 1u);
  return (unsigned short)(x >> 16);
}
__device__ __forceinline__ unsigned packf(float v) {
  unsigned short hi = f2bf(v);
  unsigned short lo = f2bf(v - bf2f(hi));
  return (unsigned)hi | ((unsigned)lo << 16);
}
__device__ __forceinline__ float unpackf(unsigned u) {
  return bf2f((unsigned short)(u & 0xFFFF)) + bf2f((unsigned short)(u >> 16));
}
__device__ __forceinline__ float sigm(float x) { return 1.0f / (1.0f + __expf(-x)); }
__device__ __forceinline__ float rin(const void* p, size_t i, bool f32) {
  return f32 ? ((const float*)p)[i] : bf2f(((const unsigned short*)p)[i]);
}
__device__ __forceinline__ bf16y8 ld8(const unsigned short* p) {
  return __builtin_bit_cast(bf16y8, *(const bf16s8*)p);
}

// agent-scope relaxed atomics: sc1 accesses at the L3 coherence point
__device__ __forceinline__ unsigned ald(const unsigned* p) {
  return __hip_atomic_load(p, __ATOMIC_RELAXED, __HIP_MEMORY_SCOPE_AGENT);
}
__device__ __forceinline__ void ast(unsigned* p, unsigned v) {
  __hip_atomic_store(p, v, __ATOMIC_RELAXED, __HIP_MEMORY_SCOPE_AGENT);
}

struct KArgs {
  const void* in[27];
  float* out;
  float* kappa;
  unsigned *xu;               // packed x, 307200
  unsigned *wu;               // packed w, 8192
  unsigned *h1[2], *h2[2], *h3[2];  // packed h planes, 32768 each
  unsigned* bar;              // [0] full cnt; [32/64/96/128] grp cnts; [256+] per-WG flags
};

// LDS B-fragment fill, hi/lo planes
__device__ void fillB(unsigned short* Bhi, unsigned short* Blo, const void* Wih,
                      const void* Whh, int KP, int ihCols, int ihEnd, int hhStart,
                      int q, int tid, bool f32) {
  int total = KP * 16;
  for (int idx = tid; idx < total; idx += 256) {
    int k = idx >> 4, n = idx & 15;
    int row = (n >> 2) * HH + q * 4 + (n & 3);
    float v = 0.f;
    if (k < 3) v = rin(Wih, (size_t)row * ihCols + k, f32);
    else if (k >= 8 && k < ihEnd) v = rin(Wih, (size_t)row * ihCols + (k - 5), f32);
    else if (k >= hhStart && k < hhStart + 256) v = rin(Whh, (size_t)row * HH + (k - hhStart), f32);
    unsigned short hi = f2bf(v);
    int a = ((k >> 3) * 16 + n) * 8 + (k & 7);
    Bhi[a] = hi;
    Blo[a] = f2bf(v - bf2f(hi));
  }
}

// MFMA hi/lo gate stage; waves 0,1 cover the group's 32 batches (2 M-tiles).
// A regions: kc0/quad0 -> x(3), [8,72) -> w, [72,328) -> r2, [328,584) -> r3.
template <int KC, bool R3>
__device__ __forceinline__ void gate_mfma(
    const unsigned* __restrict__ xt, const unsigned* __restrict__ wu,
    const unsigned* __restrict__ r2, const unsigned* __restrict__ r3,
    const unsigned short* __restrict__ Bhi, const unsigned short* __restrict__ Blo,
    const float* __restrict__ bias4, float& creg, unsigned* __restrict__ hout,
    int grp, int q, float* zls, int tid) {
  const int wave = tid >> 6, lane = tid & 63;
  if (wave >= 2) return;   // waves 2,3 idle during gates (MFMA not the bottleneck)
  const int n15 = lane & 15, quad = lane >> 4;
  const int b = grp * GB + wave * 16 + n15;

  unsigned xv0 = 0, xv1 = 0, xv2 = 0;
  if (quad == 0) {
    xv0 = ald(xt + b * 3 + 0);
    xv1 = ald(xt + b * 3 + 1);
    xv2 = ald(xt + b * 3 + 2);
  }

  constexpr int DEP = 8;
  unsigned long long buf[DEP][4];

  auto issue = [&](int kc) {
    const int k0 = kc * 32 + quad * 8;
    const unsigned* p;
    if (kc == 0 && quad == 0) p = nullptr;
    else if (k0 < 72) p = wu + b * 64 + (k0 - 8);
    else if (k0 < 328) p = r2 + b * 256 + (k0 - 72);
    else if (R3 && k0 < 584) p = r3 + b * 256 + (k0 - 328);
    else p = nullptr;
    unsigned long long* d = buf[kc & (DEP - 1)];
    if (p) {
      const unsigned long long* q8 = (const unsigned long long*)p;
#pragma unroll
      for (int j = 0; j < 4; ++j)
        d[j] = __hip_atomic_load(q8 + j, __ATOMIC_RELAXED, __HIP_MEMORY_SCOPE_AGENT);
    } else {
#pragma unroll
      for (int j = 0; j < 4; ++j) d[j] = 0ull;
    }
  };

#pragma unroll
  for (int kc = 0; kc < DEP && kc < KC; ++kc) issue(kc);

  f32x4 acc = {0.f, 0.f, 0.f, 0.f};
#pragma unroll
  for (int kc = 0; kc < KC; ++kc) {
    unsigned long long* s = buf[kc & (DEP - 1)];
    bf16s8 th, tl;
#pragma unroll
    for (int j = 0; j < 4; ++j) {
      unsigned lo32 = (unsigned)s[j], hi32 = (unsigned)(s[j] >> 32);
      th[2 * j] = (short)(lo32 & 0xFFFFu);     tl[2 * j] = (short)(lo32 >> 16);
      th[2 * j + 1] = (short)(hi32 & 0xFFFFu); tl[2 * j + 1] = (short)(hi32 >> 16);
    }
    if (kc == 0 && quad == 0) {
      th[0] = (short)(xv0 & 0xFFFFu); tl[0] = (short)(xv0 >> 16);
      th[1] = (short)(xv1 & 0xFFFFu); tl[1] = (short)(xv1 >> 16);
      th[2] = (short)(xv2 & 0xFFFFu); tl[2] = (short)(xv2 >> 16);
    }
    bf16y8 ah = __builtin_bit_cast(bf16y8, th);
    bf16y8 al = __builtin_bit_cast(bf16y8, tl);
    const int boff = ((kc * 4 + quad) * 16 + n15) * 8;
    bf16y8 bh = ld8(Bhi + boff), bl = ld8(Blo + boff);
    acc = __builtin_amdgcn_mfma_f32_16x16x32_bf16(ah, bh, acc, 0, 0, 0);
    acc = __builtin_amdgcn_mfma_f32_16x16x32_bf16(ah, bl, acc, 0, 0, 0);
    acc = __builtin_amdgcn_mfma_f32_16x16x32_bf16(al, bh, acc, 0, 0, 0);
    if (kc + DEP < KC) issue(kc + DEP);
  }

  // wave-private LDS transpose
  float* zw = zls + wave * (16 * 17);
#pragma unroll
  for (int r = 0; r < 4; ++r) zw[(quad * 4 + r) * 17 + n15] = acc[r];
  const int m = lane >> 2, j = lane & 3;
  const int hu = q * 4 + j;
  const int bb = grp * GB + wave * 16 + m;
  float zi = zw[m * 17 + (0 + j)]  + bias4[0];
  float zf = zw[m * 17 + (4 + j)]  + bias4[1];
  float zg = zw[m * 17 + (8 + j)]  + bias4[2];
  float zo = zw[m * 17 + (12 + j)] + bias4[3];
  float cn = sigm(zf) * creg + sigm(zi) * tanhf(zg);
  creg = cn;
  float hn = sigm(zo) * tanhf(cn);
  ast(hout + bb * HH + hu, packf(hn));
}

// Attention window for batch b (whole WG).
template <bool F32>
__device__ void window_stage(const KArgs& a, int b, const unsigned* __restrict__ h1c,
                             int tid, float* misc) {
  float* shm  = misc;        // 256
  float* part = misc + 256;  // 240
  float* win  = misc + 500;  // 30
  float* kap  = misc + 530;  // 10
  float* phi  = misc + 544;  // 64
  shm[tid] = unpackf(ald(h1c + b * HH + tid));
  __syncthreads();
  if (tid < 240) {
    int r = tid >> 3, pp = tid & 7;
    float s = 0.f;
#pragma unroll 8
    for (int i = 0; i < 32; ++i) s += rin(a.in[11], r * HH + pp * 32 + i, F32) * shm[pp * 32 + i];
    part[tid] = s;
  }
  __syncthreads();
  if (tid < 30) {
    float s = rin(a.in[12], tid, F32);
#pragma unroll
    for (int i = 0; i < 8; ++i) s += part[tid * 8 + i];
    win[tid] = __expf(s);
  }
  __syncthreads();
  if (tid < 10) {
    float kp = a.kappa[b * KK + tid] + 0.1f * win[20 + tid];
    a.kappa[b * KK + tid] = kp;
    kap[tid] = kp;
  }
  __syncthreads();
  if (tid < 64) {
    float u = (float)tid, s = 0.f;
#pragma unroll
    for (int r = 0; r < 10; ++r) {
      float d = kap[r] - u;
      s += win[r] * __expf(-win[10 + r] * d * d);
    }
    phi[tid] = s;
  }
  __syncthreads();
  if (tid < 64) {
    float s = 0.f;
    for (int u = 0; u < 64; ++u) s += phi[u] * rin(a.in[1], ((size_t)b * UU + u) * AA + tid, F32);
    ast(a.wu + b * AA + tid, packf(s));
  }
}

// Output projections for timestep tt, batch b (whole WG).
template <bool F32>
__device__ void proj_stage(const KArgs& a, int tt, const unsigned* __restrict__ h3b,
                           int b, int tid, float* misc) {
  float* shm  = misc;        // 256
  float* part = misc + 256;  // 242
  float* zp   = misc + 500;  // 121
  shm[tid] = unpackf(ald(h3b + b * HH + tid));
  __syncthreads();
  if (tid < 242) {
    int o = tid >> 1, hf = tid & 1;
    const void* Wt;
    const void* bt;
    int rr;
    if (o == 0) {
      Wt = a.in[13]; bt = a.in[14]; rr = 0;
    } else {
      int fam = (o - 1) / 20;
      rr = (o - 1) % 20;
      Wt = a.in[15 + fam * 2];
      bt = a.in[16 + fam * 2];
    }
    float s0 = hf ? 0.f : rin(bt, rr, F32), s1 = 0.f;
    const float* hh = shm + hf * 128;
#pragma unroll 8
    for (int i = 0; i < 128; i += 2) {
      s0 += rin(Wt, (size_t)rr * HH + hf * 128 + i, F32) * hh[i];
      s1 += rin(Wt, (size_t)rr * HH + hf * 128 + i + 1, F32) * hh[i + 1];
    }
    part[tid] = s0 + s1;
  }
  __syncthreads();
  if (tid < 121) zp[tid] = part[tid * 2] + part[tid * 2 + 1];
  __syncthreads();
  size_t tb = (size_t)tt * BB + b;
  if (tid == 0) {
    a.out[tb] = 1.f / (1.f + __expf(zp[0]));  // sigmoid(-z)
  } else if (tid < 121) {
    int fam = (tid - 1) / 20, g = (tid - 1) % 20;
    float z = zp[tid];
    float val;
    if (fam == 0) {
      float mx = -1e30f;
      for (int jj = 0; jj < 20; ++jj) mx = fmaxf(mx, zp[1 + jj]);
      float den = 0.f;
      for (int jj = 0; jj < 20; ++jj) den += __expf(zp[1 + jj] - mx);
      val = __expf(z - mx) / den;
    } else if (fam <= 2) {
      val = z;
    } else if (fam <= 4) {
      val = __expf(z);
    } else {
      val = tanhf(z);
    }
    a.out[(size_t)102400 + (size_t)fam * 2048000 + tb * GG + g] = val;
  }
}

#define BAR_WORDS (256 + NWG * 32)

__global__ void __launch_bounds__(256) bar_init_kernel(unsigned* bar) {
  for (int i = threadIdx.x; i < BAR_WORDS; i += 256) bar[i] = 0u;
}

__global__ void __launch_bounds__(256, 1) hsm_kernel(KArgs a) {
  __shared__ unsigned short B1h[5632], B1l[5632];
  __shared__ unsigned short B2h[9728], B2l[9728];
  __shared__ unsigned short B3h[9728], B3l[9728];
  __shared__ float zls[4 * 16 * 17];
  __shared__ float misc[768];
  __shared__ unsigned islast;

  const int tid = threadIdx.x;
  const int wg = blockIdx.x;
  const int grp = wg >> 6;   // batch group of 32
  const int q = wg & 63;     // hidden quad
  unsigned* cnt_full = a.bar;
  unsigned* cnt_grp  = a.bar + 32 * (1 + grp);
  unsigned* flags    = a.bar + 256;
  unsigned* myflag   = flags + wg * 32;

  auto barrier = [&](unsigned* cnt, unsigned target, unsigned fv, int nfl, int flbase) {
    __syncthreads();
    if (tid == 0) {
      unsigned old = __hip_atomic_fetch_add(cnt, 1u, __ATOMIC_RELAXED,
                                            __HIP_MEMORY_SCOPE_AGENT);
      islast = (old == target - 1u) ? 1u : 0u;
    }
    __syncthreads();
    if (islast) {
      if (tid < nfl) ast(flags + (flbase + tid) * 32, fv);
    } else if (tid == 0) {
      while (ald(myflag) < fv) __builtin_amdgcn_s_sleep(2);
    }
    __syncthreads();
  };

  // ---- dtype sniff (uniform) ----
  bool isf32;
  {
    const unsigned short* w = (const unsigned short*)a.in[3];
    int cnt = 0;
    for (int i = 0; i < 128; ++i) {
      float v = bf2f(w[i]);
      if (!(fabsf(v) <= 100.f)) cnt++;
    }
    isf32 = (cnt > 0);
  }

  // ---- init (all cross-WG state through sc1 atomics) ----
  const int g0 = wg * 256 + tid, gs = 65536;
  if (isf32) {
    const float* xp = (const float*)a.in[0];
    for (int i = g0; i < 307200; i += gs) ast(a.xu + i, packf(xp[i]));
  } else {
    const unsigned short* xp = (const unsigned short*)a.in[0];
    for (int i = g0; i < 307200; i += gs) ast(a.xu + i, (unsigned)xp[i]);
  }
  if (g0 < 32768) {
    ast(a.h1[0] + g0, 0u); ast(a.h1[1] + g0, 0u);
    ast(a.h2[0] + g0, 0u); ast(a.h2[1] + g0, 0u);
    ast(a.h3[0] + g0, 0u); ast(a.h3[1] + g0, 0u);
  }
  if (g0 < 8192) ast(a.wu + g0, 0x00003F80u);   // w init = 1.0
  if (q < GB && tid < KK) a.kappa[(grp * GB + q) * KK + tid] = 0.f;

  float bs1[4], bs2[4], bs3[4];
  {
    const int hu = q * 4 + (tid & 3);
#pragma unroll
    for (int g = 0; g < 4; ++g) {
      bs1[g] = rin(a.in[4], g * HH + hu, isf32);
      bs2[g] = rin(a.in[7], g * HH + hu, isf32);
      bs3[g] = rin(a.in[10], g * HH + hu, isf32);
    }
  }
  float c1r = 0.f, c2r = 0.f, c3r = 0.f;

  fillB(B1h, B1l, a.in[2], a.in[3], 352, 67, 72, 72, q, tid, isf32);
  fillB(B2h, B2l, a.in[5], a.in[6], 608, 323, 328, 328, q, tid, isf32);
  fillB(B3h, B3l, a.in[8], a.in[9], 608, 323, 328, 328, q, tid, isf32);
  barrier(cnt_full, NWG, 1, NWG, 0);   // full grid once

  unsigned ph = 0;

  // prologue: LSTM1(t=0): rec h1[0]=0, w=ones -> h1[1]
  gate_mfma<11, false>(a.xu, a.wu, a.h1[0], nullptr, B1h, B1l, bs1, c1r,
                       a.h1[1], grp, q, zls, tid);
  ++ph; barrier(cnt_grp, ph * 64u, ph + 1u, 64, grp * 64);

  for (int t = 0; t < TT; ++t) {
    const int p = t & 1;
    const unsigned* xt = a.xu + (size_t)t * BB * 3;
    // Stage B: window(t) on WGs q<32, proj(t-1) on WGs q>=32 (parallel)
    if (q < GB) {
      if (isf32) window_stage<true>(a, grp * GB + q, a.h1[1 - p], tid, misc);
      else       window_stage<false>(a, grp * GB + q, a.h1[1 - p], tid, misc);
    } else if (t > 0) {
      if (isf32) proj_stage<true>(a, t - 1, a.h3[p], grp * GB + q - GB, tid, misc);
      else       proj_stage<false>(a, t - 1, a.h3[p], grp * GB + q - GB, tid, misc);
    }
    ++ph; barrier(cnt_grp, ph * 64u, ph + 1u, 64, grp * 64);
    // Stage C: LSTM2(t)
    gate_mfma<19, true>(xt, a.wu, a.h1[1 - p], a.h2[p], B2h, B2l,
                        bs2, c2r, a.h2[1 - p], grp, q, zls, tid);
    ++ph; barrier(cnt_grp, ph * 64u, ph + 1u, 64, grp * 64);
    // Stage D: LSTM3(t) + LSTM1(t+1)
    gate_mfma<19, true>(xt, a.wu, a.h2[1 - p], a.h3[p], B3h, B3l,
                        bs3, c3r, a.h3[1 - p], grp, q, zls, tid);
    if (t < TT - 1) {
      gate_mfma<11, false>(xt + BB * 3, a.wu, a.h1[1 - p], nullptr,
                           B1h, B1l, bs1, c1r, a.h1[p], grp, q, zls, tid);
    }
    ++ph; barrier(cnt_grp, ph * 64u, ph + 1u, 64, grp * 64);
  }
  if (q >= GB) {
    if (isf32) proj_stage<true>(a, TT - 1, a.h3[0], grp * GB + q - GB, tid, misc);
    else       proj_stage<false>(a, TT - 1, a.h3[0], grp * GB + q - GB, tid, misc);
  }
}

extern "C" void kernel_launch(void* const* d_in, const int* in_sizes, int n_in,
                              void* d_out, int out_size, void* d_ws, size_t ws_size,
                              hipStream_t stream) {
  KArgs a;
  for (int i = 0; i < 27; ++i) a.in[i] = d_in[i];
  a.out = (float*)d_out;

  char* ws = (char*)d_ws;
  size_t off = 0;
  auto take = [&](size_t bytes) {
    void* p = ws + off;
    off = (off + bytes + 127) & ~(size_t)127;
    return p;
  };
  a.kappa = (float*)take(1280 * 4);
  a.wu    = (unsigned*)take(8192 * 4);
  a.h1[0] = (unsigned*)take(32768 * 4);
  a.h1[1] = (unsigned*)take(32768 * 4);
  a.h2[0] = (unsigned*)take(32768 * 4);
  a.h2[1] = (unsigned*)take(32768 * 4);
  a.h3[0] = (unsigned*)take(32768 * 4);
  a.h3[1] = (unsigned*)take(32768 * 4);
  a.xu    = (unsigned*)take(307200 * 4);
  a.bar   = (unsigned*)take(BAR_WORDS * 4);

  bar_init_kernel<<<1, 256, 0, stream>>>(a.bar);
  hsm_kernel<<<NWG, 256, 0, stream>>>(a);
}

// Round 11
// 15794.041 us; speedup vs baseline: 15.4426x; 1.2694x over previous
//
#include <hip/hip_runtime.h>

#define TT 800
#define BB 128
#define HH 256
#define UU 64
#define AA 64
#define KK 10
#define GG 20
#define NWG 256
#define GB 32          // batches per group
#define NGRP 4

typedef float f32x4 __attribute__((ext_vector_type(4)));
typedef __bf16 bf16y8 __attribute__((ext_vector_type(8)));
typedef short bf16s8 __attribute__((ext_vector_type(8)));

__device__ __forceinline__ float bf2f(unsigned short u) {
  return __uint_as_float(((unsigned int)u) << 16);
}
__device__ __forceinline__ unsigned short f2bf(float f) {
  unsigned int x = __float_as_uint(f);
  x += 0x7FFFu + ((x >> 16) & 1u);
  return (unsigned short)(x >> 16);
}
__device__ __forceinline__ unsigned packf(float v) {
  unsigned short hi = f2bf(v);
  unsigned short lo = f2bf(v - bf2f(hi));
  return (unsigned)hi | ((unsigned)lo << 16);
}
__device__ __forceinline__ float unpackf(unsigned u) {
  return bf2f((unsigned short)(u & 0xFFFF)) + bf2f((unsigned short)(u >> 16));
}
__device__ __forceinline__ float sigm(float x) { return 1.0f / (1.0f + __expf(-x)); }
__device__ __forceinline__ float rin(const void* p, size_t i, bool f32) {
  return f32 ? ((const float*)p)[i] : bf2f(((const unsigned short*)p)[i]);
}
__device__ __forceinline__ bf16y8 ld8(const unsigned short* p) {
  return __builtin_bit_cast(bf16y8, *(const bf16s8*)p);
}

// agent-scope relaxed atomics: sc1 accesses at the L3 coherence point
__device__ __forceinline__ unsigned ald(const unsigned* p) {
  return __hip_atomic_load(p, __ATOMIC_RELAXED, __HIP_MEMORY_SCOPE_AGENT);
}
__device__ __forceinline__ void ast(unsigned* p, unsigned v) {
  __hip_atomic_store(p, v, __ATOMIC_RELAXED, __HIP_MEMORY_SCOPE_AGENT);
}

// State planes are k-major: plane[kblk][b][j], kblk=hu>>3, j=hu&7.
// Flat: kblk*1024 + b*8 + j  (1024 = BB*8). Coalesced 32B/lane-row gate reads.

struct KArgs {
  const void* in[27];
  float* out;
  float* kappa;
  unsigned *xu;               // packed x, [t][b][3], 307200
  unsigned *wu;               // packed w, k-major, 8192
  unsigned *h1[2], *h2[2], *h3[2];  // packed h planes, k-major, 32768 each
  unsigned* bar;              // [0] full cnt; [32/64/96/128] grp cnts; [256+] per-WG flags
};

// LDS B-fragment fill, hi/lo planes
__device__ void fillB(unsigned short* Bhi, unsigned short* Blo, const void* Wih,
                      const void* Whh, int KP, int ihCols, int ihEnd, int hhStart,
                      int q, int tid, bool f32) {
  int total = KP * 16;
  for (int idx = tid; idx < total; idx += 256) {
    int k = idx >> 4, n = idx & 15;
    int row = (n >> 2) * HH + q * 4 + (n & 3);
    float v = 0.f;
    if (k < 3) v = rin(Wih, (size_t)row * ihCols + k, f32);
    else if (k >= 8 && k < ihEnd) v = rin(Wih, (size_t)row * ihCols + (k - 5), f32);
    else if (k >= hhStart && k < hhStart + 256) v = rin(Whh, (size_t)row * HH + (k - hhStart), f32);
    unsigned short hi = f2bf(v);
    int a = ((k >> 3) * 16 + n) * 8 + (k & 7);
    Bhi[a] = hi;
    Blo[a] = f2bf(v - bf2f(hi));
  }
}

// MFMA hi/lo gate stage; waves 0,1 cover the group's 32 batches (2 M-tiles).
// A regions: kc0/quad0 -> x(3), [8,72) -> w, [72,328) -> r2, [328,584) -> r3.
template <int KC, bool R3>
__device__ __forceinline__ void gate_mfma(
    const unsigned* __restrict__ xt, const unsigned* __restrict__ wu,
    const unsigned* __restrict__ r2, const unsigned* __restrict__ r3,
    const unsigned short* __restrict__ Bhi, const unsigned short* __restrict__ Blo,
    const float* __restrict__ bias4, float& creg, unsigned* __restrict__ hout,
    int grp, int q, float* zls, int tid) {
  const int wave = tid >> 6, lane = tid & 63;
  if (wave >= 2) return;   // waves 2,3 idle during gates
  const int n15 = lane & 15, quad = lane >> 4;
  const int b = grp * GB + wave * 16 + n15;

  unsigned xv0 = 0, xv1 = 0, xv2 = 0;
  if (quad == 0) {
    xv0 = ald(xt + b * 3 + 0);
    xv1 = ald(xt + b * 3 + 1);
    xv2 = ald(xt + b * 3 + 2);
  }

  constexpr int DEP = 8;
  unsigned long long buf[DEP][4];

  // k-major planes: block of 8 packed elems for (kblk, b) at plane + kblk*1024 + b*8
  auto issue = [&](int kc) {
    const int k0 = kc * 32 + quad * 8;
    const unsigned* p;
    if (kc == 0 && quad == 0) p = nullptr;
    else if (k0 < 72) p = wu + ((k0 - 8) >> 3) * 1024 + b * 8;
    else if (k0 < 328) p = r2 + ((k0 - 72) >> 3) * 1024 + b * 8;
    else if (R3 && k0 < 584) p = r3 + ((k0 - 328) >> 3) * 1024 + b * 8;
    else p = nullptr;
    unsigned long long* d = buf[kc & (DEP - 1)];
    if (p) {
      const unsigned long long* q8 = (const unsigned long long*)p;
#pragma unroll
      for (int j = 0; j < 4; ++j)
        d[j] = __hip_atomic_load(q8 + j, __ATOMIC_RELAXED, __HIP_MEMORY_SCOPE_AGENT);
    } else {
#pragma unroll
      for (int j = 0; j < 4; ++j) d[j] = 0ull;
    }
  };

#pragma unroll
  for (int kc = 0; kc < DEP && kc < KC; ++kc) issue(kc);

  f32x4 acc = {0.f, 0.f, 0.f, 0.f};
#pragma unroll
  for (int kc = 0; kc < KC; ++kc) {
    unsigned long long* s = buf[kc & (DEP - 1)];
    bf16s8 th, tl;
#pragma unroll
    for (int j = 0; j < 4; ++j) {
      unsigned lo32 = (unsigned)s[j], hi32 = (unsigned)(s[j] >> 32);
      th[2 * j] = (short)(lo32 & 0xFFFFu);     tl[2 * j] = (short)(lo32 >> 16);
      th[2 * j + 1] = (short)(hi32 & 0xFFFFu); tl[2 * j + 1] = (short)(hi32 >> 16);
    }
    if (kc == 0 && quad == 0) {
      th[0] = (short)(xv0 & 0xFFFFu); tl[0] = (short)(xv0 >> 16);
      th[1] = (short)(xv1 & 0xFFFFu); tl[1] = (short)(xv1 >> 16);
      th[2] = (short)(xv2 & 0xFFFFu); tl[2] = (short)(xv2 >> 16);
    }
    bf16y8 ah = __builtin_bit_cast(bf16y8, th);
    bf16y8 al = __builtin_bit_cast(bf16y8, tl);
    const int boff = ((kc * 4 + quad) * 16 + n15) * 8;
    bf16y8 bh = ld8(Bhi + boff), bl = ld8(Blo + boff);
    acc = __builtin_amdgcn_mfma_f32_16x16x32_bf16(ah, bh, acc, 0, 0, 0);
    acc = __builtin_amdgcn_mfma_f32_16x16x32_bf16(ah, bl, acc, 0, 0, 0);
    acc = __builtin_amdgcn_mfma_f32_16x16x32_bf16(al, bh, acc, 0, 0, 0);
    if (kc + DEP < KC) issue(kc + DEP);
  }

  // wave-private LDS transpose
  float* zw = zls + wave * (16 * 17);
#pragma unroll
  for (int r = 0; r < 4; ++r) zw[(quad * 4 + r) * 17 + n15] = acc[r];
  const int m = lane >> 2, j = lane & 3;
  const int hu = q * 4 + j;
  const int bb = grp * GB + wave * 16 + m;
  float zi = zw[m * 17 + (0 + j)]  + bias4[0];
  float zf = zw[m * 17 + (4 + j)]  + bias4[1];
  float zg = zw[m * 17 + (8 + j)]  + bias4[2];
  float zo = zw[m * 17 + (12 + j)] + bias4[3];
  float cn = sigm(zf) * creg + sigm(zi) * tanhf(zg);
  creg = cn;
  float hn = sigm(zo) * tanhf(cn);
  ast(hout + (hu >> 3) * 1024 + bb * 8 + (hu & 7), packf(hn));
}

// Attention window for batch b (whole WG).
template <bool F32>
__device__ void window_stage(const KArgs& a, int b, const unsigned* __restrict__ h1c,
                             int tid, float* misc) {
  float* shm  = misc;        // 256
  float* part = misc + 256;  // 240
  float* win  = misc + 500;  // 30
  float* kap  = misc + 530;  // 10
  float* phi  = misc + 544;  // 64
  shm[tid] = unpackf(ald(h1c + (tid >> 3) * 1024 + b * 8 + (tid & 7)));
  __syncthreads();
  if (tid < 240) {
    int r = tid >> 3, pp = tid & 7;
    float s = 0.f;
#pragma unroll 8
    for (int i = 0; i < 32; ++i) s += rin(a.in[11], r * HH + pp * 32 + i, F32) * shm[pp * 32 + i];
    part[tid] = s;
  }
  __syncthreads();
  if (tid < 30) {
    float s = rin(a.in[12], tid, F32);
#pragma unroll
    for (int i = 0; i < 8; ++i) s += part[tid * 8 + i];
    win[tid] = __expf(s);
  }
  __syncthreads();
  if (tid < 10) {
    float kp = a.kappa[b * KK + tid] + 0.1f * win[20 + tid];
    a.kappa[b * KK + tid] = kp;
    kap[tid] = kp;
  }
  __syncthreads();
  if (tid < 64) {
    float u = (float)tid, s = 0.f;
#pragma unroll
    for (int r = 0; r < 10; ++r) {
      float d = kap[r] - u;
      s += win[r] * __expf(-win[10 + r] * d * d);
    }
    phi[tid] = s;
  }
  __syncthreads();
  if (tid < 64) {
    float s = 0.f;
    for (int u = 0; u < 64; ++u) s += phi[u] * rin(a.in[1], ((size_t)b * UU + u) * AA + tid, F32);
    ast(a.wu + (tid >> 3) * 1024 + b * 8 + (tid & 7), packf(s));
  }
}

// Output projections for timestep tt, batch b (whole WG).
template <bool F32>
__device__ void proj_stage(const KArgs& a, int tt, const unsigned* __restrict__ h3b,
                           int b, int tid, float* misc) {
  float* shm  = misc;        // 256
  float* part = misc + 256;  // 242
  float* zp   = misc + 500;  // 121
  shm[tid] = unpackf(ald(h3b + (tid >> 3) * 1024 + b * 8 + (tid & 7)));
  __syncthreads();
  if (tid < 242) {
    int o = tid >> 1, hf = tid & 1;
    const void* Wt;
    const void* bt;
    int rr;
    if (o == 0) {
      Wt = a.in[13]; bt = a.in[14]; rr = 0;
    } else {
      int fam = (o - 1) / 20;
      rr = (o - 1) % 20;
      Wt = a.in[15 + fam * 2];
      bt = a.in[16 + fam * 2];
    }
    float s0 = hf ? 0.f : rin(bt, rr, F32), s1 = 0.f;
    const float* hh = shm + hf * 128;
#pragma unroll 8
    for (int i = 0; i < 128; i += 2) {
      s0 += rin(Wt, (size_t)rr * HH + hf * 128 + i, F32) * hh[i];
      s1 += rin(Wt, (size_t)rr * HH + hf * 128 + i + 1, F32) * hh[i + 1];
    }
    part[tid] = s0 + s1;
  }
  __syncthreads();
  if (tid < 121) zp[tid] = part[tid * 2] + part[tid * 2 + 1];
  __syncthreads();
  size_t tb = (size_t)tt * BB + b;
  if (tid == 0) {
    a.out[tb] = 1.f / (1.f + __expf(zp[0]));  // sigmoid(-z)
  } else if (tid < 121) {
    int fam = (tid - 1) / 20, g = (tid - 1) % 20;
    float z = zp[tid];
    float val;
    if (fam == 0) {
      float mx = -1e30f;
      for (int jj = 0; jj < 20; ++jj) mx = fmaxf(mx, zp[1 + jj]);
      float den = 0.f;
      for (int jj = 0; jj < 20; ++jj) den += __expf(zp[1 + jj] - mx);
      val = __expf(z - mx) / den;
    } else if (fam <= 2) {
      val = z;
    } else if (fam <= 4) {
      val = __expf(z);
    } else {
      val = tanhf(z);
    }
    a.out[(size_t)102400 + (size_t)fam * 2048000 + tb * GG + g] = val;
  }
}

#define BAR_WORDS (256 + NWG * 32)

__global__ void __launch_bounds__(256) bar_init_kernel(unsigned* bar) {
  for (int i = threadIdx.x; i < BAR_WORDS; i += 256) bar[i] = 0u;
}

__global__ void __launch_bounds__(256, 1) hsm_kernel(KArgs a) {
  __shared__ unsigned short B1h[5632], B1l[5632];
  __shared__ unsigned short B2h[9728], B2l[9728];
  __shared__ unsigned short B3h[9728], B3l[9728];
  __shared__ float zls[4 * 16 * 17];
  __shared__ float misc[768];
  __shared__ unsigned islast;

  const int tid = threadIdx.x;
  const int wg = blockIdx.x;
  const int grp = wg >> 6;   // batch group of 32
  const int q = wg & 63;     // hidden quad
  unsigned* cnt_full = a.bar;
  unsigned* cnt_grp  = a.bar + 32 * (1 + grp);
  unsigned* flags    = a.bar + 256;
  unsigned* myflag   = flags + wg * 32;

  auto barrier = [&](unsigned* cnt, unsigned target, unsigned fv, int nfl, int flbase) {
    __syncthreads();
    if (tid == 0) {
      unsigned old = __hip_atomic_fetch_add(cnt, 1u, __ATOMIC_RELAXED,
                                            __HIP_MEMORY_SCOPE_AGENT);
      islast = (old == target - 1u) ? 1u : 0u;
    }
    __syncthreads();
    if (islast) {
      if (tid < nfl) ast(flags + (flbase + tid) * 32, fv);
    } else if (tid == 0) {
      while (ald(myflag) < fv) __builtin_amdgcn_s_sleep(2);
    }
    __syncthreads();
  };

  // ---- dtype sniff (uniform) ----
  bool isf32;
  {
    const unsigned short* w = (const unsigned short*)a.in[3];
    int cnt = 0;
    for (int i = 0; i < 128; ++i) {
      float v = bf2f(w[i]);
      if (!(fabsf(v) <= 100.f)) cnt++;
    }
    isf32 = (cnt > 0);
  }

  // ---- init (all cross-WG state through sc1 atomics) ----
  const int g0 = wg * 256 + tid, gs = 65536;
  if (isf32) {
    const float* xp = (const float*)a.in[0];
    for (int i = g0; i < 307200; i += gs) ast(a.xu + i, packf(xp[i]));
  } else {
    const unsigned short* xp = (const unsigned short*)a.in[0];
    for (int i = g0; i < 307200; i += gs) ast(a.xu + i, (unsigned)xp[i]);
  }
  if (g0 < 32768) {
    ast(a.h1[0] + g0, 0u); ast(a.h1[1] + g0, 0u);
    ast(a.h2[0] + g0, 0u); ast(a.h2[1] + g0, 0u);
    ast(a.h3[0] + g0, 0u); ast(a.h3[1] + g0, 0u);
  }
  if (g0 < 8192) ast(a.wu + g0, 0x00003F80u);   // w init = 1.0 (uniform in any layout)
  if (q < GB && tid < KK) a.kappa[(grp * GB + q) * KK + tid] = 0.f;

  float bs1[4], bs2[4], bs3[4];
  {
    const int hu = q * 4 + (tid & 3);
#pragma unroll
    for (int g = 0; g < 4; ++g) {
      bs1[g] = rin(a.in[4], g * HH + hu, isf32);
      bs2[g] = rin(a.in[7], g * HH + hu, isf32);
      bs3[g] = rin(a.in[10], g * HH + hu, isf32);
    }
  }
  float c1r = 0.f, c2r = 0.f, c3r = 0.f;

  fillB(B1h, B1l, a.in[2], a.in[3], 352, 67, 72, 72, q, tid, isf32);
  fillB(B2h, B2l, a.in[5], a.in[6], 608, 323, 328, 328, q, tid, isf32);
  fillB(B3h, B3l, a.in[8], a.in[9], 608, 323, 328, 328, q, tid, isf32);
  barrier(cnt_full, NWG, 1, NWG, 0);   // full grid once

  unsigned ph = 0;

  // prologue: LSTM1(t=0): rec h1[0]=0, w=ones -> h1[1]
  gate_mfma<11, false>(a.xu, a.wu, a.h1[0], nullptr, B1h, B1l, bs1, c1r,
                       a.h1[1], grp, q, zls, tid);
  ++ph; barrier(cnt_grp, ph * 64u, ph + 1u, 64, grp * 64);

  for (int t = 0; t < TT; ++t) {
    const int p = t & 1;
    const unsigned* xt = a.xu + (size_t)t * BB * 3;
    // Stage B: window(t) on WGs q<32, proj(t-1) on WGs q>=32 (parallel)
    if (q < GB) {
      if (isf32) window_stage<true>(a, grp * GB + q, a.h1[1 - p], tid, misc);
      else       window_stage<false>(a, grp * GB + q, a.h1[1 - p], tid, misc);
    } else if (t > 0) {
      if (isf32) proj_stage<true>(a, t - 1, a.h3[p], grp * GB + q - GB, tid, misc);
      else       proj_stage<false>(a, t - 1, a.h3[p], grp * GB + q - GB, tid, misc);
    }
    ++ph; barrier(cnt_grp, ph * 64u, ph + 1u, 64, grp * 64);
    // Stage C: LSTM2(t)
    gate_mfma<19, true>(xt, a.wu, a.h1[1 - p], a.h2[p], B2h, B2l,
                        bs2, c2r, a.h2[1 - p], grp, q, zls, tid);
    ++ph; barrier(cnt_grp, ph * 64u, ph + 1u, 64, grp * 64);
    // Stage D: LSTM3(t) + LSTM1(t+1)
    gate_mfma<19, true>(xt, a.wu, a.h2[1 - p], a.h3[p], B3h, B3l,
                        bs3, c3r, a.h3[1 - p], grp, q, zls, tid);
    if (t < TT - 1) {
      gate_mfma<11, false>(xt + BB * 3, a.wu, a.h1[1 - p], nullptr,
                           B1h, B1l, bs1, c1r, a.h1[p], grp, q, zls, tid);
    }
    ++ph; barrier(cnt_grp, ph * 64u, ph + 1u, 64, grp * 64);
  }
  if (q >= GB) {
    if (isf32) proj_stage<true>(a, TT - 1, a.h3[0], grp * GB + q - GB, tid, misc);
    else       proj_stage<false>(a, TT - 1, a.h3[0], grp * GB + q - GB, tid, misc);
  }
}

extern "C" void kernel_launch(void* const* d_in, const int* in_sizes, int n_in,
                              void* d_out, int out_size, void* d_ws, size_t ws_size,
                              hipStream_t stream) {
  KArgs a;
  for (int i = 0; i < 27; ++i) a.in[i] = d_in[i];
  a.out = (float*)d_out;

  char* ws = (char*)d_ws;
  size_t off = 0;
  auto take = [&](size_t bytes) {
    void* p = ws + off;
    off = (off + bytes + 127) & ~(size_t)127;
    return p;
  };
  a.kappa = (float*)take(1280 * 4);
  a.wu    = (unsigned*)take(8192 * 4);
  a.h1[0] = (unsigned*)take(32768 * 4);
  a.h1[1] = (unsigned*)take(32768 * 4);
  a.h2[0] = (unsigned*)take(32768 * 4);
  a.h2[1] = (unsigned*)take(32768 * 4);
  a.h3[0] = (unsigned*)take(32768 * 4);
  a.h3[1] = (unsigned*)take(32768 * 4);
  a.xu    = (unsigned*)take(307200 * 4);
  a.bar   = (unsigned*)take(BAR_WORDS * 4);

  bar_init_kernel<<<1, 256, 0, stream>>>(a.bar);
  hsm_kernel<<<NWG, 256, 0, stream>>>(a);
}